// Round 8
// baseline (1458.820 us; speedup 1.0000x reference)
//
#include <hip/hip_runtime.h>
#include <hip/hip_fp16.h>
#include <math.h>

// SpectralGCN: GRU over T -> normalized Laplacian -> top-10 spectral filter
// (G=L*L^T, symmetric-tile powers to G^32, 6x subspace applies with CholQR,
//  Rayleigh-Ritz 2-barrier shared-coefficient Jacobi, 3 sweeps) ->
//  3 fused conv layers (factored M, W folded) -> linear out fused.
// Sizes: B=64, N=1024, F=8, T=12, H=32, K=10, OUT=12.

#define NN 1024
#define PP 48
#define JSWEEPS 3

// ---------------- GRU ----------------
__global__ __launch_bounds__(128) void k_gru(
    const float* __restrict__ x, const float* __restrict__ wih,
    const float* __restrict__ whh, const float* __restrict__ bih,
    const float* __restrict__ bhh, float* __restrict__ hout) {
  __shared__ __half s_x[64][98];  // f16 staging: halves LDS, occupancy up
  __shared__ float s_h[64][33];
  int tid = threadIdx.x;
  int row = tid & 63;
  int i_base = __builtin_amdgcn_readfirstlane((tid >> 6) * 16);
  long row0 = (long)blockIdx.x * 64;

  for (int i = tid; i < 64 * 24; i += 128) {
    int r = i / 24, c = i % 24;
    float4 v = *(const float4*)&x[(row0 + r) * 96 + c * 4];
    s_x[r][c * 4 + 0] = __float2half(v.x);
    s_x[r][c * 4 + 1] = __float2half(v.y);
    s_x[r][c * 4 + 2] = __float2half(v.z);
    s_x[r][c * 4 + 3] = __float2half(v.w);
  }
  for (int i = tid; i < 64 * 32; i += 128) s_h[i / 32][i % 32] = 0.f;
  __syncthreads();

  float h[32];
#pragma unroll
  for (int k = 0; k < 32; ++k) h[k] = 0.f;

  for (int t = 0; t < 12; ++t) {
    float x8[8];
#pragma unroll
    for (int f = 0; f < 8; ++f) x8[f] = __half2float(s_x[row][f * 12 + t]);
    for (int ii = 0; ii < 16; ++ii) {
      int i = i_base + ii;
      float ar = bih[i] + bhh[i];
      float az = bih[32 + i] + bhh[32 + i];
      float gx = bih[64 + i];
      float gh = bhh[64 + i];
#pragma unroll
      for (int f = 0; f < 8; ++f) {
        ar += x8[f] * wih[i * 8 + f];
        az += x8[f] * wih[(32 + i) * 8 + f];
        gx += x8[f] * wih[(64 + i) * 8 + f];
      }
#pragma unroll
      for (int k = 0; k < 32; ++k) {
        ar += h[k] * whh[i * 32 + k];
        az += h[k] * whh[(32 + i) * 32 + k];
        gh += h[k] * whh[(64 + i) * 32 + k];
      }
      ar = fminf(fmaxf(ar, -30.f), 30.f);
      az = fminf(fmaxf(az, -30.f), 30.f);
      float r = __frcp_rn(1.f + __expf(-ar));
      float z = __frcp_rn(1.f + __expf(-az));
      float a = gx + r * gh;
      a = fminf(fmaxf(a, -15.f), 15.f);
      float e2 = __expf(2.f * a);
      float n = (e2 - 1.f) * __frcp_rn(e2 + 1.f);
      float hold = s_h[row][i];
      s_h[row][i] = (1.f - z) * n + z * hold;
    }
    __syncthreads();
#pragma unroll
    for (int k = 0; k < 32; ++k) h[k] = s_h[row][k];
    __syncthreads();
  }
  float* hp = hout + (row0 + row) * 32 + i_base;
#pragma unroll
  for (int k = 0; k < 16; k += 4) {
    float4 v = make_float4(h[i_base + k], h[i_base + k + 1],
                           h[i_base + k + 2], h[i_base + k + 3]);
    *(float4*)&hp[k] = v;
  }
}

// ---------------- graph build ----------------
__global__ void k_scatter(const int* __restrict__ ei, const float* __restrict__ ew,
                          float* __restrict__ A, int E) {
  int e = blockIdx.x * 256 + threadIdx.x;
  if (e < E) atomicAdd(&A[ei[e] * NN + ei[E + e]], ew[e]);
}

__global__ __launch_bounds__(256) void k_degree(const float* __restrict__ A,
                                                float* __restrict__ disq) {
  __shared__ float red[256];
  int row = blockIdx.x, tid = threadIdx.x;
  float s = 0.f;
  for (int j = tid; j < NN; j += 256) s += A[row * NN + j];
  red[tid] = s;
  __syncthreads();
  for (int off = 128; off > 0; off >>= 1) {
    if (tid < off) red[tid] += red[tid + off];
    __syncthreads();
  }
  if (tid == 0) disq[row] = 1.f / sqrtf(red[0]);
}

__global__ void k_lap(float* __restrict__ A, const float* __restrict__ disq) {
  int idx = blockIdx.x * 256 + threadIdx.x;
  int i = idx >> 10, j = idx & 1023;
  float v = -disq[i] * A[idx] * disq[j];
  if (i == j) v += 1.f;
  A[idx] = v;
}

// ------ C = A*A^T (symmetric): upper-tri tiles only + mirror store --------
__global__ __launch_bounds__(256) void k_mm_sym(const float* __restrict__ A,
                                                float* __restrict__ C) {
  if (blockIdx.x < blockIdx.y) return;   // only j0 >= i0
  __shared__ float As[32][68];
  __shared__ float Bs[32][68];
  int tid = threadIdx.x;
  int tx = tid & 15, ty = tid >> 4;
  int i0 = blockIdx.y * 64, j0 = blockIdx.x * 64;
  float acc[4][4];
#pragma unroll
  for (int a = 0; a < 4; ++a)
#pragma unroll
    for (int b = 0; b < 4; ++b) acc[a][b] = 0.f;
  int lrow = tid >> 3;
  int kk0 = (tid & 7) * 4;
  float4 pa0 = *(const float4*)&A[(long)(i0 + lrow) * NN + kk0];
  float4 pa1 = *(const float4*)&A[(long)(i0 + lrow + 32) * NN + kk0];
  float4 pb0 = *(const float4*)&A[(long)(j0 + lrow) * NN + kk0];
  float4 pb1 = *(const float4*)&A[(long)(j0 + lrow + 32) * NN + kk0];
  for (int k0 = 0; k0 < NN; k0 += 32) {
    As[kk0 + 0][lrow] = pa0.x; As[kk0 + 1][lrow] = pa0.y;
    As[kk0 + 2][lrow] = pa0.z; As[kk0 + 3][lrow] = pa0.w;
    As[kk0 + 0][lrow + 32] = pa1.x; As[kk0 + 1][lrow + 32] = pa1.y;
    As[kk0 + 2][lrow + 32] = pa1.z; As[kk0 + 3][lrow + 32] = pa1.w;
    Bs[kk0 + 0][lrow] = pb0.x; Bs[kk0 + 1][lrow] = pb0.y;
    Bs[kk0 + 2][lrow] = pb0.z; Bs[kk0 + 3][lrow] = pb0.w;
    Bs[kk0 + 0][lrow + 32] = pb1.x; Bs[kk0 + 1][lrow + 32] = pb1.y;
    Bs[kk0 + 2][lrow + 32] = pb1.z; Bs[kk0 + 3][lrow + 32] = pb1.w;
    __syncthreads();
    if (k0 + 32 < NN) {
      pa0 = *(const float4*)&A[(long)(i0 + lrow) * NN + k0 + 32 + kk0];
      pa1 = *(const float4*)&A[(long)(i0 + lrow + 32) * NN + k0 + 32 + kk0];
      pb0 = *(const float4*)&A[(long)(j0 + lrow) * NN + k0 + 32 + kk0];
      pb1 = *(const float4*)&A[(long)(j0 + lrow + 32) * NN + k0 + 32 + kk0];
    }
#pragma unroll
    for (int kk = 0; kk < 32; ++kk) {
      float4 av = *(const float4*)&As[kk][ty * 4];
      float4 bv = *(const float4*)&Bs[kk][tx * 4];
      float aa[4] = {av.x, av.y, av.z, av.w};
      float bb[4] = {bv.x, bv.y, bv.z, bv.w};
#pragma unroll
      for (int a = 0; a < 4; ++a)
#pragma unroll
        for (int b = 0; b < 4; ++b) acc[a][b] += aa[a] * bb[b];
    }
    __syncthreads();
  }
#pragma unroll
  for (int a = 0; a < 4; ++a) {
    float4 v = make_float4(acc[a][0], acc[a][1], acc[a][2], acc[a][3]);
    *(float4*)&C[(long)(i0 + ty * 4 + a) * NN + j0 + tx * 4] = v;
  }
  if (i0 != j0) {  // mirror: C[j][i] = C[i][j]
#pragma unroll
    for (int a = 0; a < 4; ++a)
#pragma unroll
      for (int b = 0; b < 4; ++b)
        C[(long)(j0 + tx * 4 + b) * NN + i0 + ty * 4 + a] = acc[a][b];
  }
}

// ---------------- subspace iteration ----------------
__global__ void k_q0(float* __restrict__ Q) {
  int i = blockIdx.x * 256 + threadIdx.x;
  if (i < NN * PP) {
    unsigned u = (unsigned)i * 2654435761u;
    u ^= u >> 16; u *= 2246822519u; u ^= u >> 13; u *= 3266489917u; u ^= u >> 16;
    Q[i] = (float)(u & 0xFFFFFF) * (1.f / 16777216.f) - 0.5f;
  }
}

__global__ __launch_bounds__(256) void k_spmm(const float* __restrict__ Gp,
                                              const float* __restrict__ Q,
                                              float* __restrict__ Zp) {
  __shared__ float Qs[64][49];
  __shared__ float Gs[16][65];
  int tid = threadIdx.x;
  int r = tid >> 4;
  int c0 = (tid & 15) * 3;
  int row0 = blockIdx.x * 16;
  int k0 = blockIdx.y * 256;
  float a0 = 0.f, a1 = 0.f, a2 = 0.f;
  for (int kt = 0; kt < 4; ++kt) {
    int kb = k0 + kt * 64;
    for (int idx = tid; idx < 64 * PP; idx += 256) {
      int qr = idx / PP, qc = idx % PP;
      Qs[qr][qc] = Q[(kb + qr) * PP + qc];
    }
    for (int idx = tid; idx < 16 * 64; idx += 256) {
      int gr = idx >> 6, gk = idx & 63;
      Gs[gr][gk] = Gp[(long)(row0 + gr) * NN + kb + gk];
    }
    __syncthreads();
#pragma unroll 4
    for (int kk = 0; kk < 64; ++kk) {
      float g = Gs[r][kk];
      a0 += g * Qs[kk][c0];
      a1 += g * Qs[kk][c0 + 1];
      a2 += g * Qs[kk][c0 + 2];
    }
    __syncthreads();
  }
  float* zp = Zp + (long)blockIdx.y * (NN * PP);
  zp[(row0 + r) * PP + c0] = a0;
  zp[(row0 + r) * PP + c0 + 1] = a1;
  zp[(row0 + r) * PP + c0 + 2] = a2;
}

// Sum 4 partials -> Z, per-block Gram partial Sp[blk].
__global__ __launch_bounds__(256) void k_gram(const float* __restrict__ Zp,
                                              float* __restrict__ Z,
                                              float* __restrict__ Sp) {
  __shared__ float Zs[32][49];
  int tid = threadIdx.x;
  int r0 = blockIdx.x * 32;
  for (int idx = tid; idx < 32 * PP; idx += 256) {
    int r = idx / PP, c = idx % PP;
    long g = (long)(r0 + r) * PP + c;
    float s = Zp[g] + Zp[g + NN * PP] + Zp[g + 2 * NN * PP] + Zp[g + 3 * NN * PP];
    Zs[r][c] = s;
    Z[g] = s;
  }
  __syncthreads();
  float* sp = Sp + blockIdx.x * (PP * PP);
  for (int cell = tid; cell < PP * PP; cell += 256) {
    int i = cell / PP, j = cell % PP;
    float a = 0.f;
#pragma unroll 8
    for (int r = 0; r < 32; ++r) a += Zs[r][i] * Zs[r][j];
    sp[cell] = a;
  }
}

__global__ __launch_bounds__(256) void k_tbuild(const float* __restrict__ Qa,
                                                const float* __restrict__ Zp,
                                                float* __restrict__ Tp) {
  __shared__ float Qs[32][49];
  __shared__ float Ys[32][49];
  int tid = threadIdx.x;
  int r0 = blockIdx.x * 32;
  for (int idx = tid; idx < 32 * PP; idx += 256) {
    int r = idx / PP, c = idx % PP;
    long g = (long)(r0 + r) * PP + c;
    Qs[r][c] = Qa[g];
    Ys[r][c] = Zp[g] + Zp[g + NN * PP] + Zp[g + 2 * NN * PP] + Zp[g + 3 * NN * PP];
  }
  __syncthreads();
  float* tp = Tp + blockIdx.x * (PP * PP);
  for (int cell = tid; cell < PP * PP; cell += 256) {
    int i = cell / PP, j = cell % PP;
    float a = 0.f;
#pragma unroll 8
    for (int r = 0; r < 32; ++r) a += Qs[r][i] * Ys[r][j];
    tp[cell] = a;
  }
}

// Fused CholQR apply: factorize summed Gram, rows solve y R = q in registers.
__global__ __launch_bounds__(256) void k_qr(const float* __restrict__ Sp,
                                            float* __restrict__ Q) {
  __shared__ float R[PP][PP + 1];
  __shared__ float rs[PP];
  __shared__ float idiag[PP];
  int tid = threadIdx.x;
  for (int idx = tid; idx < PP * PP; idx += 256) {
    float s = 0.f;
    for (int b = 0; b < 32; ++b) s += Sp[b * (PP * PP) + idx];
    R[idx / PP][idx % PP] = s;
  }
  __syncthreads();
  for (int j = 0; j < PP; ++j) {
    float d = R[j][j];
    float sq = sqrtf(d > 1e-30f ? d : 1e-30f);
    float invd = 1.f / sq;
    for (int c = j + tid; c < PP; c += 256)
      rs[c] = (c == j) ? sq : R[j][c] * invd;
    __syncthreads();
    int m = PP - 1 - j;
    for (int idx = tid; idx < m * m; idx += 256) {
      int i = j + 1 + idx / m, c = j + 1 + idx % m;
      R[i][c] -= rs[i] * rs[c];
    }
    for (int c = j + tid; c < PP; c += 256) R[j][c] = rs[c];
    __syncthreads();
  }
  if (tid < PP) idiag[tid] = 1.f / R[tid][tid];
  __syncthreads();
  int row = blockIdx.x * 256 + tid;
  float q[PP];
#pragma unroll
  for (int k = 0; k < PP; ++k) q[k] = Q[row * PP + k];
#pragma unroll
  for (int c = 0; c < PP; ++c) {
    float s = q[c];
#pragma unroll
    for (int k = 0; k < c; ++k) s -= q[k] * R[k][c];
    q[c] = s * idiag[c];
  }
#pragma unroll
  for (int k = 0; k < PP; ++k) Q[row * PP + k] = q[k];
}

// Shared-coefficient ping-pong cyclic Jacobi (2 barriers/round), 3 sweeps;
// top-10 select via wave-0 shfl butterfly. Exact 2x2 diagonalization handles
// near-degenerate clusters (where perturbative Ritz failed, round 7).
__global__ __launch_bounds__(384) void k_jacobi(const float* __restrict__ Tp,
                                                float* __restrict__ Vsel,
                                                float* __restrict__ s10) {
  __shared__ float Ta[PP][PP + 1], Tb[PP][PP + 1];
  __shared__ float Va[PP][PP + 1], Vb[PP][PP + 1];
  __shared__ float w0[PP], w1[PP];
  __shared__ int j0a[PP], j1a[PP];
  __shared__ int selidx[10];
  int tid = threadIdx.x;
  for (int idx = tid; idx < PP * PP; idx += 384) {
    float s = 0.f;
    for (int b = 0; b < 32; ++b) s += Tp[b * (PP * PP) + idx];
    Tb[idx / PP][idx % PP] = s;
  }
  __syncthreads();
  for (int idx = tid; idx < PP * PP; idx += 384) {
    int i = idx / PP, j = idx % PP;
    Ta[i][j] = 0.5f * (Tb[i][j] + Tb[j][i]);
    Va[i][j] = (i == j) ? 1.f : 0.f;
  }
  __syncthreads();
  float (*Tc)[PP + 1] = Ta, (*Tn)[PP + 1] = Tb;
  float (*Vc)[PP + 1] = Va, (*Vn)[PP + 1] = Vb;
  int i_row = tid >> 3;
  int jb = (tid & 7) * 6;
  for (int sweep = 0; sweep < JSWEEPS; ++sweep) {
    for (int r = 0; r < PP - 1; ++r) {
      if (tid < 24) {
        int k = tid;
        int p = (k == 0) ? 0 : ((r + k - 1) % 47) + 1;
        int q = ((r + 46 - k) % 47) + 1;
        float app = Tc[p][p], aqq = Tc[q][q], apq = Tc[p][q];
        float c = 1.f, s = 0.f;
        if (fabsf(apq) > 1e-30f) {
          float tau = (aqq - app) / (2.f * apq);
          float den = fabsf(tau) + sqrtf(1.f + tau * tau);
          float tt = copysignf(1.f / den, tau);
          c = 1.f / sqrtf(1.f + tt * tt);
          s = tt * c;
        }
        j0a[p] = p; j1a[p] = q; w0[p] = c;  w1[p] = -s;
        j0a[q] = p; j1a[q] = q; w0[q] = s;  w1[q] = c;
      }
      __syncthreads();
      float wi0 = w0[i_row], wi1 = w1[i_row];
      int i0 = j0a[i_row], i1 = j1a[i_row];
      float tnew[6], vnew[6];
#pragma unroll
      for (int m = 0; m < 6; ++m) {
        int j = jb + m;
        float wj0 = w0[j], wj1 = w1[j];
        int a = j0a[j], b = j1a[j];
        tnew[m] = wi0 * (wj0 * Tc[i0][a] + wj1 * Tc[i0][b]) +
                  wi1 * (wj0 * Tc[i1][a] + wj1 * Tc[i1][b]);
        vnew[m] = wj0 * Vc[i_row][a] + wj1 * Vc[i_row][b];
      }
#pragma unroll
      for (int m = 0; m < 6; ++m) {
        Tn[i_row][jb + m] = tnew[m];
        Vn[i_row][jb + m] = vnew[m];
      }
      __syncthreads();
      float (*tt_)[PP + 1] = Tc; Tc = Tn; Tn = tt_;
      float (*vt_)[PP + 1] = Vc; Vc = Vn; Vn = vt_;
    }
  }
  if (tid < 64) {
    float v = (tid < PP) ? Tc[tid][tid] : -1e30f;
    for (int sel = 0; sel < 10; ++sel) {
      float bv = v; int bi = tid;
      for (int off = 32; off > 0; off >>= 1) {
        float ov = __shfl_xor(bv, off);
        int oi = __shfl_xor(bi, off);
        if (ov > bv || (ov == bv && oi < bi)) { bv = ov; bi = oi; }
      }
      if (tid == 0) { selidx[sel] = bi; s10[sel] = sqrtf(fmaxf(bv, 0.f)); }
      if (tid == bi) v = -1e30f;
    }
  }
  __syncthreads();
  for (int idx = tid; idx < PP * 10; idx += 384) {
    int j = idx / 10, i = idx % 10;
    Vsel[idx] = Vc[j][selidx[i]];
  }
}

// U10 = Qa * Vsel. grid 4 x 256.
__global__ __launch_bounds__(256) void k_u10(const float* __restrict__ Q,
                                             const float* __restrict__ Vsel,
                                             float* __restrict__ U10) {
  __shared__ float Vs[PP * 10];
  int tid = threadIdx.x;
  for (int idx = tid; idx < PP * 10; idx += 256) Vs[idx] = Vsel[idx];
  __syncthreads();
  int row = blockIdx.x * 256 + tid;
  float q[PP];
#pragma unroll
  for (int k = 0; k < PP; ++k) q[k] = Q[row * PP + k];
#pragma unroll
  for (int i = 0; i < 10; ++i) {
    float s = 0.f;
#pragma unroll
    for (int k = 0; k < PP; ++k) s += q[k] * Vs[k * 10 + i];
    U10[row * 10 + i] = s;
  }
}

// ------- fused conv layer: P0=U^T h, P1=s.*(P0 W), h+=relu(U P1) ----------
// LAST also emits out = h_new @ lw + lb. grid 64 (one block per batch).
template <int LAST>
__global__ __launch_bounds__(320) void k_layer(float* __restrict__ h,
    const float* __restrict__ U10, const float* __restrict__ W,
    const float* __restrict__ s10, const float* __restrict__ lw,
    const float* __restrict__ lb, float* __restrict__ out) {
  __shared__ float Hs[128][33];
  __shared__ float Us[128][10];
  __shared__ float P0s[10][33];
  __shared__ float P1s[10][32];
  __shared__ float Ws[32][32];
  __shared__ float lws[32][12];
  __shared__ float lbs[12];
  int tid = threadIdx.x, b = blockIdx.x;
  int i = tid / 32, kk = tid % 32;
  for (int idx = tid; idx < 1024; idx += 320) Ws[idx / 32][idx % 32] = W[idx];
  if (LAST) {
    for (int idx = tid; idx < 384; idx += 320) lws[idx / 12][idx % 12] = lw[idx];
    if (tid < 12) lbs[tid] = lb[tid];
  }
  float acc = 0.f;
  for (int t0 = 0; t0 < NN; t0 += 128) {
    for (int idx = tid; idx < 128 * 32; idx += 320) {
      int r = idx / 32, c = idx % 32;
      Hs[r][c] = h[(long)(b * NN + t0 + r) * 32 + c];
    }
    for (int idx = tid; idx < 1280; idx += 320)
      Us[idx / 10][idx % 10] = U10[(t0 + idx / 10) * 10 + idx % 10];
    __syncthreads();
#pragma unroll 8
    for (int r = 0; r < 128; ++r) acc += Us[r][i] * Hs[r][kk];
    __syncthreads();
  }
  P0s[i][kk] = acc;
  __syncthreads();
  float aa = 0.f;
#pragma unroll
  for (int j = 0; j < 32; ++j) aa += P0s[i][j] * Ws[j][kk];
  P1s[i][kk] = s10[i] * aa;
  __syncthreads();
  for (int t0 = 0; t0 < NN; t0 += 128) {
    for (int idx = tid; idx < 1280; idx += 320)
      Us[idx / 10][idx % 10] = U10[(t0 + idx / 10) * 10 + idx % 10];
    __syncthreads();
    for (int idx = tid; idx < 128 * 32; idx += 320) {
      int r = idx / 32, k = idx % 32;
      float z = 0.f;
#pragma unroll
      for (int q = 0; q < 10; ++q) z += Us[r][q] * P1s[q][k];
      long g = (long)(b * NN + t0 + r) * 32 + k;
      float hn = h[g] + fmaxf(z, 0.f);
      if (LAST) Hs[r][k] = hn;
      else h[g] = hn;
    }
    if (LAST) {
      __syncthreads();
      for (int idx = tid; idx < 128 * 12; idx += 320) {
        int r = idx / 12, o = idx % 12;
        float s = lbs[o];
#pragma unroll
        for (int j = 0; j < 32; ++j) s += Hs[r][j] * lws[j][o];
        out[(long)(b * NN + t0 + r) * 12 + o] = s;
      }
    }
    __syncthreads();
  }
}

extern "C" void kernel_launch(void* const* d_in, const int* in_sizes, int n_in,
                              void* d_out, int out_size, void* d_ws, size_t ws_size,
                              hipStream_t stream) {
  const float* x    = (const float*)d_in[0];
  const int*   ei   = (const int*)d_in[1];
  const float* ew   = (const float*)d_in[2];
  const float* wih  = (const float*)d_in[3];
  const float* whh  = (const float*)d_in[4];
  const float* bih  = (const float*)d_in[5];
  const float* bhh  = (const float*)d_in[6];
  const float* convw = (const float*)d_in[7];
  const float* lw   = (const float*)d_in[8];
  const float* lb   = (const float*)d_in[9];
  float* out = (float*)d_out;
  float* ws  = (float*)d_ws;
  int E = in_sizes[1] / 2;

  float* h    = ws;                 // 2097152
  float* B1   = h + 2097152;        // 1048576
  float* B2   = B1 + 1048576;       // 1048576
  float* B3   = B2 + 1048576;       // 1048576
  float* Qa   = B3 + 1048576;       // 49152
  float* Qb   = Qa + 49152;         // 49152
  float* Zp   = Qb + 49152;         // 196608
  float* Sp   = Zp + 196608;        // 73728
  float* Tp   = Sp + 73728;         // 73728
  float* Vsel = Tp + 73728;         // 480
  float* s10  = Vsel + 480;         // 16
  float* U10  = s10 + 16;           // 10240
  float* disq = U10 + 10240;        // 1024

  // Stage A: GRU
  k_gru<<<1024, 128, 0, stream>>>(x, wih, whh, bih, bhh, h);

  // Stage B: Laplacian (B1) and symmetric powers: B2=G, B3=G^32
  hipMemsetAsync(B1, 0, (size_t)1048576 * 4, stream);
  k_scatter<<<(E + 255) / 256, 256, 0, stream>>>(ei, ew, B1, E);
  k_degree<<<NN, 256, 0, stream>>>(B1, disq);
  k_lap<<<4096, 256, 0, stream>>>(B1, disq);
  k_mm_sym<<<dim3(16, 16), 256, 0, stream>>>(B1, B2);  // G = L L^T
  k_mm_sym<<<dim3(16, 16), 256, 0, stream>>>(B2, B3);  // G^2
  k_mm_sym<<<dim3(16, 16), 256, 0, stream>>>(B3, B1);  // G^4
  k_mm_sym<<<dim3(16, 16), 256, 0, stream>>>(B1, B3);  // G^8
  k_mm_sym<<<dim3(16, 16), 256, 0, stream>>>(B3, B1);  // G^16
  k_mm_sym<<<dim3(16, 16), 256, 0, stream>>>(B1, B3);  // G^32

  // Stage C: 6 applies of G^32 (=192 powers), CholQR after each
  k_q0<<<192, 256, 0, stream>>>(Qa);
  for (int it = 0; it < 6; ++it) {
    float* src = (it & 1) ? Qb : Qa;
    float* dst = (it & 1) ? Qa : Qb;
    k_spmm<<<dim3(64, 4), 256, 0, stream>>>(B3, src, Zp);
    k_gram<<<32, 256, 0, stream>>>(Zp, dst, Sp);
    k_qr<<<4, 256, 0, stream>>>(Sp, dst);
  }
  // final orthonormal basis in Qa

  // Rayleigh-Ritz with G (exact Jacobi, 3 sweeps)
  k_spmm<<<dim3(64, 4), 256, 0, stream>>>(B2, Qa, Zp);
  k_tbuild<<<32, 256, 0, stream>>>(Qa, Zp, Tp);
  k_jacobi<<<1, 384, 0, stream>>>(Tp, Vsel, s10);
  k_u10<<<4, 256, 0, stream>>>(Qa, Vsel, U10);

  // Stage D: fused conv layers
  k_layer<0><<<64, 320, 0, stream>>>(h, U10, convw, s10, lw, lb, out);
  k_layer<0><<<64, 320, 0, stream>>>(h, U10, convw + 1024, s10, lw, lb, out);
  k_layer<1><<<64, 320, 0, stream>>>(h, U10, convw + 2048, s10, lw, lb, out);
}

// Round 9
// 1270.497 us; speedup vs baseline: 1.1482x; 1.1482x over previous
//
#include <hip/hip_runtime.h>
#include <math.h>

// SpectralGCN: GRU over T -> normalized Laplacian -> top-10 spectral filter
// (G=L*L^T, symmetric-tile powers to G^32, 6x subspace applies with CholQR,
//  Rayleigh-Ritz 2-barrier shared-coefficient Jacobi, 3 sweeps) ->
//  3 conv layers (factored M, W folded into projection) -> fused linear out.
// Sizes: B=64, N=1024, F=8, T=12, H=32, K=10, OUT=12.

#define NN 1024
#define PP 48
#define JSWEEPS 3

// ---------------- GRU ----------------
// 4 waves/block, 64 rows/block; wave w computes channels [8w, 8w+8) for all
// rows (weight addresses wave-uniform -> s_load). 16 waves/CU occupancy.
__global__ __launch_bounds__(256) void k_gru(
    const float* __restrict__ x, const float* __restrict__ wih,
    const float* __restrict__ whh, const float* __restrict__ bih,
    const float* __restrict__ bhh, float* __restrict__ hout) {
  __shared__ float s_x[64][97];
  __shared__ float s_h[64][33];
  int tid = threadIdx.x;
  int row = tid & 63;
  int i_base = __builtin_amdgcn_readfirstlane((tid >> 6) * 8);
  long row0 = (long)blockIdx.x * 64;

  for (int i = tid; i < 64 * 24; i += 256) {
    int r = i / 24, c = i % 24;
    float4 v = *(const float4*)&x[(row0 + r) * 96 + c * 4];
    s_x[r][c * 4 + 0] = v.x; s_x[r][c * 4 + 1] = v.y;
    s_x[r][c * 4 + 2] = v.z; s_x[r][c * 4 + 3] = v.w;
  }
  for (int i = tid; i < 64 * 32; i += 256) s_h[i / 32][i % 32] = 0.f;
  __syncthreads();

  float h[32];
#pragma unroll
  for (int k = 0; k < 32; ++k) h[k] = 0.f;

  for (int t = 0; t < 12; ++t) {
    float x8[8];
#pragma unroll
    for (int f = 0; f < 8; ++f) x8[f] = s_x[row][f * 12 + t];
    for (int ii = 0; ii < 8; ++ii) {
      int i = i_base + ii;                  // wave-uniform
      float ar = bih[i] + bhh[i];
      float az = bih[32 + i] + bhh[32 + i];
      float gx = bih[64 + i];
      float gh = bhh[64 + i];
#pragma unroll
      for (int f = 0; f < 8; ++f) {
        ar += x8[f] * wih[i * 8 + f];
        az += x8[f] * wih[(32 + i) * 8 + f];
        gx += x8[f] * wih[(64 + i) * 8 + f];
      }
#pragma unroll
      for (int k = 0; k < 32; ++k) {
        ar += h[k] * whh[i * 32 + k];
        az += h[k] * whh[(32 + i) * 32 + k];
        gh += h[k] * whh[(64 + i) * 32 + k];
      }
      ar = fminf(fmaxf(ar, -30.f), 30.f);
      az = fminf(fmaxf(az, -30.f), 30.f);
      float r = __frcp_rn(1.f + __expf(-ar));
      float z = __frcp_rn(1.f + __expf(-az));
      float a = gx + r * gh;
      a = fminf(fmaxf(a, -15.f), 15.f);
      float e2 = __expf(2.f * a);
      float n = (e2 - 1.f) * __frcp_rn(e2 + 1.f);
      float hold = s_h[row][i];             // own cell, no race
      s_h[row][i] = (1.f - z) * n + z * hold;
    }
    __syncthreads();                        // all channels of h(t) written
#pragma unroll
    for (int k = 0; k < 32; ++k) h[k] = s_h[row][k];
    __syncthreads();                        // protect next iter's writes
  }
  // coalesced writeout straight from LDS (no runtime-indexed reg array)
  for (int idx = tid; idx < 64 * 8; idx += 256) {
    int r = idx >> 3, c4 = idx & 7;
    float4 v = make_float4(s_h[r][c4 * 4], s_h[r][c4 * 4 + 1],
                           s_h[r][c4 * 4 + 2], s_h[r][c4 * 4 + 3]);
    *(float4*)&hout[(row0 + r) * 32 + c4 * 4] = v;
  }
}

// ---------------- graph build ----------------
__global__ void k_scatter(const int* __restrict__ ei, const float* __restrict__ ew,
                          float* __restrict__ A, int E) {
  int e = blockIdx.x * 256 + threadIdx.x;
  if (e < E) atomicAdd(&A[ei[e] * NN + ei[E + e]], ew[e]);
}

__global__ __launch_bounds__(256) void k_degree(const float* __restrict__ A,
                                                float* __restrict__ disq) {
  __shared__ float red[256];
  int row = blockIdx.x, tid = threadIdx.x;
  float s = 0.f;
  for (int j = tid; j < NN; j += 256) s += A[row * NN + j];
  red[tid] = s;
  __syncthreads();
  for (int off = 128; off > 0; off >>= 1) {
    if (tid < off) red[tid] += red[tid + off];
    __syncthreads();
  }
  if (tid == 0) disq[row] = 1.f / sqrtf(red[0]);
}

__global__ void k_lap(float* __restrict__ A, const float* __restrict__ disq) {
  int idx = blockIdx.x * 256 + threadIdx.x;
  int i = idx >> 10, j = idx & 1023;
  float v = -disq[i] * A[idx] * disq[j];
  if (i == j) v += 1.f;
  A[idx] = v;
}

// ------ C = A*A^T (symmetric): upper-tri tiles + LDS-transposed mirror ----
__global__ __launch_bounds__(256) void k_mm_sym(const float* __restrict__ A,
                                                float* __restrict__ C) {
  if (blockIdx.x < blockIdx.y) return;   // only j0 >= i0
  __shared__ float As[32][68];
  __shared__ float Bs[32][68];
  __shared__ float Ts[64][65];
  int tid = threadIdx.x;
  int tx = tid & 15, ty = tid >> 4;
  int i0 = blockIdx.y * 64, j0 = blockIdx.x * 64;
  float acc[4][4];
#pragma unroll
  for (int a = 0; a < 4; ++a)
#pragma unroll
    for (int b = 0; b < 4; ++b) acc[a][b] = 0.f;
  int lrow = tid >> 3;
  int kk0 = (tid & 7) * 4;
  float4 pa0 = *(const float4*)&A[(long)(i0 + lrow) * NN + kk0];
  float4 pa1 = *(const float4*)&A[(long)(i0 + lrow + 32) * NN + kk0];
  float4 pb0 = *(const float4*)&A[(long)(j0 + lrow) * NN + kk0];
  float4 pb1 = *(const float4*)&A[(long)(j0 + lrow + 32) * NN + kk0];
  for (int k0 = 0; k0 < NN; k0 += 32) {
    As[kk0 + 0][lrow] = pa0.x; As[kk0 + 1][lrow] = pa0.y;
    As[kk0 + 2][lrow] = pa0.z; As[kk0 + 3][lrow] = pa0.w;
    As[kk0 + 0][lrow + 32] = pa1.x; As[kk0 + 1][lrow + 32] = pa1.y;
    As[kk0 + 2][lrow + 32] = pa1.z; As[kk0 + 3][lrow + 32] = pa1.w;
    Bs[kk0 + 0][lrow] = pb0.x; Bs[kk0 + 1][lrow] = pb0.y;
    Bs[kk0 + 2][lrow] = pb0.z; Bs[kk0 + 3][lrow] = pb0.w;
    Bs[kk0 + 0][lrow + 32] = pb1.x; Bs[kk0 + 1][lrow + 32] = pb1.y;
    Bs[kk0 + 2][lrow + 32] = pb1.z; Bs[kk0 + 3][lrow + 32] = pb1.w;
    __syncthreads();
    if (k0 + 32 < NN) {
      pa0 = *(const float4*)&A[(long)(i0 + lrow) * NN + k0 + 32 + kk0];
      pa1 = *(const float4*)&A[(long)(i0 + lrow + 32) * NN + k0 + 32 + kk0];
      pb0 = *(const float4*)&A[(long)(j0 + lrow) * NN + k0 + 32 + kk0];
      pb1 = *(const float4*)&A[(long)(j0 + lrow + 32) * NN + k0 + 32 + kk0];
    }
#pragma unroll
    for (int kk = 0; kk < 32; ++kk) {
      float4 av = *(const float4*)&As[kk][ty * 4];
      float4 bv = *(const float4*)&Bs[kk][tx * 4];
      float aa[4] = {av.x, av.y, av.z, av.w};
      float bb[4] = {bv.x, bv.y, bv.z, bv.w};
#pragma unroll
      for (int a = 0; a < 4; ++a)
#pragma unroll
        for (int b = 0; b < 4; ++b) acc[a][b] += aa[a] * bb[b];
    }
    __syncthreads();
  }
#pragma unroll
  for (int a = 0; a < 4; ++a) {
    float4 v = make_float4(acc[a][0], acc[a][1], acc[a][2], acc[a][3]);
    *(float4*)&C[(long)(i0 + ty * 4 + a) * NN + j0 + tx * 4] = v;
  }
  if (i0 != j0) {  // mirror via LDS transpose, coalesced float4 stores
#pragma unroll
    for (int a = 0; a < 4; ++a)
#pragma unroll
      for (int b = 0; b < 4; ++b)
        Ts[tx * 4 + b][ty * 4 + a] = acc[a][b];
    __syncthreads();
    for (int idx = tid; idx < 64 * 16; idx += 256) {
      int r = idx >> 4, c4 = idx & 15;
      float4 v = make_float4(Ts[r][c4 * 4], Ts[r][c4 * 4 + 1],
                             Ts[r][c4 * 4 + 2], Ts[r][c4 * 4 + 3]);
      *(float4*)&C[(long)(j0 + r) * NN + i0 + c4 * 4] = v;
    }
  }
}

// ---------------- subspace iteration ----------------
__global__ void k_q0(float* __restrict__ Q) {
  int i = blockIdx.x * 256 + threadIdx.x;
  if (i < NN * PP) {
    unsigned u = (unsigned)i * 2654435761u;
    u ^= u >> 16; u *= 2246822519u; u ^= u >> 13; u *= 3266489917u; u ^= u >> 16;
    Q[i] = (float)(u & 0xFFFFFF) * (1.f / 16777216.f) - 0.5f;
  }
}

__global__ __launch_bounds__(256) void k_spmm(const float* __restrict__ Gp,
                                              const float* __restrict__ Q,
                                              float* __restrict__ Zp) {
  __shared__ float Qs[64][49];
  __shared__ float Gs[16][65];
  int tid = threadIdx.x;
  int r = tid >> 4;
  int c0 = (tid & 15) * 3;
  int row0 = blockIdx.x * 16;
  int k0 = blockIdx.y * 256;
  float a0 = 0.f, a1 = 0.f, a2 = 0.f;
  for (int kt = 0; kt < 4; ++kt) {
    int kb = k0 + kt * 64;
    for (int idx = tid; idx < 64 * PP; idx += 256) {
      int qr = idx / PP, qc = idx % PP;
      Qs[qr][qc] = Q[(kb + qr) * PP + qc];
    }
    for (int idx = tid; idx < 16 * 64; idx += 256) {
      int gr = idx >> 6, gk = idx & 63;
      Gs[gr][gk] = Gp[(long)(row0 + gr) * NN + kb + gk];
    }
    __syncthreads();
#pragma unroll 4
    for (int kk = 0; kk < 64; ++kk) {
      float g = Gs[r][kk];
      a0 += g * Qs[kk][c0];
      a1 += g * Qs[kk][c0 + 1];
      a2 += g * Qs[kk][c0 + 2];
    }
    __syncthreads();
  }
  float* zp = Zp + (long)blockIdx.y * (NN * PP);
  zp[(row0 + r) * PP + c0] = a0;
  zp[(row0 + r) * PP + c0 + 1] = a1;
  zp[(row0 + r) * PP + c0 + 2] = a2;
}

// Sum 4 partials -> Z, per-block Gram partial Sp[blk].
__global__ __launch_bounds__(256) void k_gram(const float* __restrict__ Zp,
                                              float* __restrict__ Z,
                                              float* __restrict__ Sp) {
  __shared__ float Zs[32][49];
  int tid = threadIdx.x;
  int r0 = blockIdx.x * 32;
  for (int idx = tid; idx < 32 * PP; idx += 256) {
    int r = idx / PP, c = idx % PP;
    long g = (long)(r0 + r) * PP + c;
    float s = Zp[g] + Zp[g + NN * PP] + Zp[g + 2 * NN * PP] + Zp[g + 3 * NN * PP];
    Zs[r][c] = s;
    Z[g] = s;
  }
  __syncthreads();
  float* sp = Sp + blockIdx.x * (PP * PP);
  for (int cell = tid; cell < PP * PP; cell += 256) {
    int i = cell / PP, j = cell % PP;
    float a = 0.f;
#pragma unroll 8
    for (int r = 0; r < 32; ++r) a += Zs[r][i] * Zs[r][j];
    sp[cell] = a;
  }
}

__global__ __launch_bounds__(256) void k_tbuild(const float* __restrict__ Qa,
                                                const float* __restrict__ Zp,
                                                float* __restrict__ Tp) {
  __shared__ float Qs[32][49];
  __shared__ float Ys[32][49];
  int tid = threadIdx.x;
  int r0 = blockIdx.x * 32;
  for (int idx = tid; idx < 32 * PP; idx += 256) {
    int r = idx / PP, c = idx % PP;
    long g = (long)(r0 + r) * PP + c;
    Qs[r][c] = Qa[g];
    Ys[r][c] = Zp[g] + Zp[g + NN * PP] + Zp[g + 2 * NN * PP] + Zp[g + 3 * NN * PP];
  }
  __syncthreads();
  float* tp = Tp + blockIdx.x * (PP * PP);
  for (int cell = tid; cell < PP * PP; cell += 256) {
    int i = cell / PP, j = cell % PP;
    float a = 0.f;
#pragma unroll 8
    for (int r = 0; r < 32; ++r) a += Qs[r][i] * Ys[r][j];
    tp[cell] = a;
  }
}

// Fused CholQR apply: factorize summed Gram, rows solve y R = q in registers.
__global__ __launch_bounds__(256) void k_qr(const float* __restrict__ Sp,
                                            float* __restrict__ Q) {
  __shared__ float R[PP][PP + 1];
  __shared__ float rs[PP];
  __shared__ float idiag[PP];
  int tid = threadIdx.x;
  for (int idx = tid; idx < PP * PP; idx += 256) {
    float s = 0.f;
    for (int b = 0; b < 32; ++b) s += Sp[b * (PP * PP) + idx];
    R[idx / PP][idx % PP] = s;
  }
  __syncthreads();
  for (int j = 0; j < PP; ++j) {
    float d = R[j][j];
    float sq = sqrtf(d > 1e-30f ? d : 1e-30f);
    float invd = 1.f / sq;
    for (int c = j + tid; c < PP; c += 256)
      rs[c] = (c == j) ? sq : R[j][c] * invd;
    __syncthreads();
    int m = PP - 1 - j;
    for (int idx = tid; idx < m * m; idx += 256) {
      int i = j + 1 + idx / m, c = j + 1 + idx % m;
      R[i][c] -= rs[i] * rs[c];
    }
    for (int c = j + tid; c < PP; c += 256) R[j][c] = rs[c];
    __syncthreads();
  }
  if (tid < PP) idiag[tid] = 1.f / R[tid][tid];
  __syncthreads();
  int row = blockIdx.x * 256 + tid;
  float q[PP];
#pragma unroll
  for (int k = 0; k < PP; ++k) q[k] = Q[row * PP + k];
#pragma unroll
  for (int c = 0; c < PP; ++c) {
    float s = q[c];
#pragma unroll
    for (int k = 0; k < c; ++k) s -= q[k] * R[k][c];
    q[c] = s * idiag[c];
  }
#pragma unroll
  for (int k = 0; k < PP; ++k) Q[row * PP + k] = q[k];
}

// Shared-coefficient ping-pong cyclic Jacobi (2 barriers/round), 3 sweeps;
// top-10 select via wave-0 shfl butterfly.
__global__ __launch_bounds__(384) void k_jacobi(const float* __restrict__ Tp,
                                                float* __restrict__ Vsel,
                                                float* __restrict__ s10) {
  __shared__ float Ta[PP][PP + 1], Tb[PP][PP + 1];
  __shared__ float Va[PP][PP + 1], Vb[PP][PP + 1];
  __shared__ float w0[PP], w1[PP];
  __shared__ int j0a[PP], j1a[PP];
  __shared__ int selidx[10];
  int tid = threadIdx.x;
  for (int idx = tid; idx < PP * PP; idx += 384) {
    float s = 0.f;
    for (int b = 0; b < 32; ++b) s += Tp[b * (PP * PP) + idx];
    Tb[idx / PP][idx % PP] = s;
  }
  __syncthreads();
  for (int idx = tid; idx < PP * PP; idx += 384) {
    int i = idx / PP, j = idx % PP;
    Ta[i][j] = 0.5f * (Tb[i][j] + Tb[j][i]);
    Va[i][j] = (i == j) ? 1.f : 0.f;
  }
  __syncthreads();
  float (*Tc)[PP + 1] = Ta, (*Tn)[PP + 1] = Tb;
  float (*Vc)[PP + 1] = Va, (*Vn)[PP + 1] = Vb;
  int i_row = tid >> 3;
  int jb = (tid & 7) * 6;
  for (int sweep = 0; sweep < JSWEEPS; ++sweep) {
    for (int r = 0; r < PP - 1; ++r) {
      if (tid < 24) {
        int k = tid;
        int p = (k == 0) ? 0 : ((r + k - 1) % 47) + 1;
        int q = ((r + 46 - k) % 47) + 1;
        float app = Tc[p][p], aqq = Tc[q][q], apq = Tc[p][q];
        float c = 1.f, s = 0.f;
        if (fabsf(apq) > 1e-30f) {
          float tau = (aqq - app) / (2.f * apq);
          float den = fabsf(tau) + sqrtf(1.f + tau * tau);
          float tt = copysignf(1.f / den, tau);
          c = 1.f / sqrtf(1.f + tt * tt);
          s = tt * c;
        }
        j0a[p] = p; j1a[p] = q; w0[p] = c;  w1[p] = -s;
        j0a[q] = p; j1a[q] = q; w0[q] = s;  w1[q] = c;
      }
      __syncthreads();
      float wi0 = w0[i_row], wi1 = w1[i_row];
      int i0 = j0a[i_row], i1 = j1a[i_row];
      float tnew[6], vnew[6];
#pragma unroll
      for (int m = 0; m < 6; ++m) {
        int j = jb + m;
        float wj0 = w0[j], wj1 = w1[j];
        int a = j0a[j], b = j1a[j];
        tnew[m] = wi0 * (wj0 * Tc[i0][a] + wj1 * Tc[i0][b]) +
                  wi1 * (wj0 * Tc[i1][a] + wj1 * Tc[i1][b]);
        vnew[m] = wj0 * Vc[i_row][a] + wj1 * Vc[i_row][b];
      }
#pragma unroll
      for (int m = 0; m < 6; ++m) {
        Tn[i_row][jb + m] = tnew[m];
        Vn[i_row][jb + m] = vnew[m];
      }
      __syncthreads();
      float (*tt_)[PP + 1] = Tc; Tc = Tn; Tn = tt_;
      float (*vt_)[PP + 1] = Vc; Vc = Vn; Vn = vt_;
    }
  }
  if (tid < 64) {
    float v = (tid < PP) ? Tc[tid][tid] : -1e30f;
    for (int sel = 0; sel < 10; ++sel) {
      float bv = v; int bi = tid;
      for (int off = 32; off > 0; off >>= 1) {
        float ov = __shfl_xor(bv, off);
        int oi = __shfl_xor(bi, off);
        if (ov > bv || (ov == bv && oi < bi)) { bv = ov; bi = oi; }
      }
      if (tid == 0) { selidx[sel] = bi; s10[sel] = sqrtf(fmaxf(bv, 0.f)); }
      if (tid == bi) v = -1e30f;
    }
  }
  __syncthreads();
  for (int idx = tid; idx < PP * 10; idx += 384) {
    int j = idx / 10, i = idx % 10;
    Vsel[idx] = Vc[j][selidx[i]];
  }
}

// U10 = Qa * Vsel. grid 4 x 256.
__global__ __launch_bounds__(256) void k_u10(const float* __restrict__ Q,
                                             const float* __restrict__ Vsel,
                                             float* __restrict__ U10) {
  __shared__ float Vs[PP * 10];
  int tid = threadIdx.x;
  for (int idx = tid; idx < PP * 10; idx += 256) Vs[idx] = Vsel[idx];
  __syncthreads();
  int row = blockIdx.x * 256 + tid;
  float q[PP];
#pragma unroll
  for (int k = 0; k < PP; ++k) q[k] = Q[row * PP + k];
#pragma unroll
  for (int i = 0; i < 10; ++i) {
    float s = 0.f;
#pragma unroll
    for (int k = 0; k < PP; ++k) s += q[k] * Vs[k * 10 + i];
    U10[row * 10 + i] = s;
  }
}

// ---------------- conv layers ----------------
// P1[b,i,k] = s10[i] * sum_j (sum_n U10[n,i] h[b,n,j]) W[j,k]
__global__ __launch_bounds__(320) void k_p0w(const float* __restrict__ h,
                                             const float* __restrict__ U10,
                                             const float* __restrict__ W,
                                             const float* __restrict__ s10,
                                             float* __restrict__ P1) {
  __shared__ float Hs[128][33];
  __shared__ float Us[128][10];
  __shared__ float P0s[10][33];
  __shared__ float Ws[32][32];
  int tid = threadIdx.x;
  int b = blockIdx.x;
  int i = tid / 32, kk = tid % 32;
  for (int idx = tid; idx < 1024; idx += 320) Ws[idx / 32][idx % 32] = W[idx];
  float acc = 0.f;
  for (int t0 = 0; t0 < NN; t0 += 128) {
    for (int idx = tid; idx < 128 * 32; idx += 320) {
      int r = idx / 32, c = idx % 32;
      Hs[r][c] = h[(long)(b * NN + t0 + r) * 32 + c];
    }
    for (int idx = tid; idx < 1280; idx += 320)
      Us[idx / 10][idx % 10] = U10[(t0 + idx / 10) * 10 + idx % 10];
    __syncthreads();
#pragma unroll 8
    for (int r = 0; r < 128; ++r) acc += Us[r][i] * Hs[r][kk];
    __syncthreads();
  }
  P0s[i][kk] = acc;
  __syncthreads();
  float a = 0.f;
#pragma unroll
  for (int j = 0; j < 32; ++j) a += P0s[i][j] * Ws[j][kk];
  P1[b * 320 + i * 32 + kk] = s10[i] * a;
}

// h += relu(U10 * P1); LAST layer also emits out = h_new @ lw + lb.
template <int LAST>
__global__ __launch_bounds__(256) void k_update(float* __restrict__ h,
                                                const float* __restrict__ U10,
                                                const float* __restrict__ P1,
                                                const float* __restrict__ lw,
                                                const float* __restrict__ lb,
                                                float* __restrict__ out) {
  __shared__ float a1[10][32];
  __shared__ float Us[64][10];
  __shared__ float hl[64][33];
  int tid = threadIdx.x;
  int b = blockIdx.x, n0 = blockIdx.y * 64;
  for (int idx = tid; idx < 320; idx += 256)
    a1[idx / 32][idx % 32] = P1[b * 320 + idx];
  for (int idx = tid; idx < 640; idx += 256)
    Us[idx / 10][idx % 10] = U10[(n0 + idx / 10) * 10 + idx % 10];
  __syncthreads();
  for (int idx = tid; idx < 2048; idx += 256) {
    int nl = idx / 32, k = idx % 32;
    float z = 0.f;
#pragma unroll
    for (int i = 0; i < 10; ++i) z += Us[nl][i] * a1[i][k];
    long g = (long)(b * NN + n0 + nl) * 32 + k;
    float hn = h[g] + fmaxf(z, 0.f);
    if (LAST) hl[nl][k] = hn;
    else h[g] = hn;
  }
  if (LAST) {
    __syncthreads();
    for (int idx = tid; idx < 64 * 12; idx += 256) {
      int row = idx / 12, o = idx % 12;
      float s = lb[o];
#pragma unroll
      for (int j = 0; j < 32; ++j) s += hl[row][j] * lw[j * 12 + o];
      out[(long)(b * NN + n0 + row) * 12 + o] = s;
    }
  }
}

extern "C" void kernel_launch(void* const* d_in, const int* in_sizes, int n_in,
                              void* d_out, int out_size, void* d_ws, size_t ws_size,
                              hipStream_t stream) {
  const float* x    = (const float*)d_in[0];
  const int*   ei   = (const int*)d_in[1];
  const float* ew   = (const float*)d_in[2];
  const float* wih  = (const float*)d_in[3];
  const float* whh  = (const float*)d_in[4];
  const float* bih  = (const float*)d_in[5];
  const float* bhh  = (const float*)d_in[6];
  const float* convw = (const float*)d_in[7];
  const float* lw   = (const float*)d_in[8];
  const float* lb   = (const float*)d_in[9];
  float* out = (float*)d_out;
  float* ws  = (float*)d_ws;
  int E = in_sizes[1] / 2;

  float* h    = ws;                 // 2097152
  float* B1   = h + 2097152;        // 1048576
  float* B2   = B1 + 1048576;       // 1048576
  float* B3   = B2 + 1048576;       // 1048576
  float* Qa   = B3 + 1048576;       // 49152
  float* Qb   = Qa + 49152;         // 49152
  float* Zp   = Qb + 49152;         // 196608
  float* Sp   = Zp + 196608;        // 73728
  float* Tp   = Sp + 73728;         // 73728
  float* Vsel = Tp + 73728;         // 480
  float* s10  = Vsel + 480;         // 16
  float* U10  = s10 + 16;           // 10240
  float* P1   = U10 + 10240;        // 20480
  float* disq = P1 + 20480;         // 1024

  // Stage A: GRU
  k_gru<<<1024, 256, 0, stream>>>(x, wih, whh, bih, bhh, h);

  // Stage B: Laplacian (B1) and symmetric powers: B2=G, B3=G^32
  hipMemsetAsync(B1, 0, (size_t)1048576 * 4, stream);
  k_scatter<<<(E + 255) / 256, 256, 0, stream>>>(ei, ew, B1, E);
  k_degree<<<NN, 256, 0, stream>>>(B1, disq);
  k_lap<<<4096, 256, 0, stream>>>(B1, disq);
  k_mm_sym<<<dim3(16, 16), 256, 0, stream>>>(B1, B2);  // G = L L^T
  k_mm_sym<<<dim3(16, 16), 256, 0, stream>>>(B2, B3);  // G^2
  k_mm_sym<<<dim3(16, 16), 256, 0, stream>>>(B3, B1);  // G^4
  k_mm_sym<<<dim3(16, 16), 256, 0, stream>>>(B1, B3);  // G^8
  k_mm_sym<<<dim3(16, 16), 256, 0, stream>>>(B3, B1);  // G^16
  k_mm_sym<<<dim3(16, 16), 256, 0, stream>>>(B1, B3);  // G^32

  // Stage C: 6 applies of G^32 (=192 powers), CholQR after each
  k_q0<<<192, 256, 0, stream>>>(Qa);
  for (int it = 0; it < 6; ++it) {
    float* src = (it & 1) ? Qb : Qa;
    float* dst = (it & 1) ? Qa : Qb;
    k_spmm<<<dim3(64, 4), 256, 0, stream>>>(B3, src, Zp);
    k_gram<<<32, 256, 0, stream>>>(Zp, dst, Sp);
    k_qr<<<4, 256, 0, stream>>>(Sp, dst);
  }
  // final orthonormal basis in Qa

  // Rayleigh-Ritz with G (exact Jacobi, 3 sweeps)
  k_spmm<<<dim3(64, 4), 256, 0, stream>>>(B2, Qa, Zp);
  k_tbuild<<<32, 256, 0, stream>>>(Qa, Zp, Tp);
  k_jacobi<<<1, 384, 0, stream>>>(Tp, Vsel, s10);
  k_u10<<<4, 256, 0, stream>>>(Qa, Vsel, U10);

  // Stage D: conv layers (split: 64-blk projection, 1024-blk update)
  for (int l = 0; l < 3; ++l) {
    k_p0w<<<64, 320, 0, stream>>>(h, U10, convw + l * 1024, s10, P1);
    if (l < 2)
      k_update<0><<<dim3(64, 16), 256, 0, stream>>>(h, U10, P1, lw, lb, out);
    else
      k_update<1><<<dim3(64, 16), 256, 0, stream>>>(h, U10, P1, lw, lb, out);
  }
}

// Round 11
// 1217.136 us; speedup vs baseline: 1.1986x; 1.0438x over previous
//
#include <hip/hip_runtime.h>
#include <math.h>

// SpectralGCN: GRU over T -> normalized Laplacian (fused into first matmul)
// -> top-10 spectral filter (G=Lap*Lap^T, symmetric-tile powers to G^32,
// 6x subspace applies with CholQR, Rayleigh-Ritz Jacobi 3 sweeps [PINNED:
// 2 sweeps failed absmax 0.0201 > 0.0184, round 10]) ->
// 3 conv layers (chunked projection + fold-in update) -> fused linear out.
// Sizes: B=64, N=1024, F=8, T=12, H=32, K=10, OUT=12.

#define NN 1024
#define PP 48
#define JSWEEPS 3

// ---------------- GRU ----------------
// 4 waves/block, 64 rows/block; wave w computes channels [8w, 8w+8).
__global__ __launch_bounds__(256) void k_gru(
    const float* __restrict__ x, const float* __restrict__ wih,
    const float* __restrict__ whh, const float* __restrict__ bih,
    const float* __restrict__ bhh, float* __restrict__ hout) {
  __shared__ float s_x[64][97];
  __shared__ float s_h[64][33];
  int tid = threadIdx.x;
  int row = tid & 63;
  int i_base = __builtin_amdgcn_readfirstlane((tid >> 6) * 8);
  long row0 = (long)blockIdx.x * 64;

  for (int i = tid; i < 64 * 24; i += 256) {
    int r = i / 24, c = i % 24;
    float4 v = *(const float4*)&x[(row0 + r) * 96 + c * 4];
    s_x[r][c * 4 + 0] = v.x; s_x[r][c * 4 + 1] = v.y;
    s_x[r][c * 4 + 2] = v.z; s_x[r][c * 4 + 3] = v.w;
  }
  for (int i = tid; i < 64 * 32; i += 256) s_h[i / 32][i % 32] = 0.f;
  __syncthreads();

  float h[32];
#pragma unroll
  for (int k = 0; k < 32; ++k) h[k] = 0.f;

  for (int t = 0; t < 12; ++t) {
    float x8[8];
#pragma unroll
    for (int f = 0; f < 8; ++f) x8[f] = s_x[row][f * 12 + t];
    for (int ii = 0; ii < 8; ++ii) {
      int i = i_base + ii;                  // wave-uniform
      float ar = bih[i] + bhh[i];
      float az = bih[32 + i] + bhh[32 + i];
      float gx = bih[64 + i];
      float gh = bhh[64 + i];
#pragma unroll
      for (int f = 0; f < 8; ++f) {
        ar += x8[f] * wih[i * 8 + f];
        az += x8[f] * wih[(32 + i) * 8 + f];
        gx += x8[f] * wih[(64 + i) * 8 + f];
      }
#pragma unroll
      for (int k = 0; k < 32; ++k) {
        ar += h[k] * whh[i * 32 + k];
        az += h[k] * whh[(32 + i) * 32 + k];
        gh += h[k] * whh[(64 + i) * 32 + k];
      }
      ar = fminf(fmaxf(ar, -30.f), 30.f);
      az = fminf(fmaxf(az, -30.f), 30.f);
      float r = __frcp_rn(1.f + __expf(-ar));
      float z = __frcp_rn(1.f + __expf(-az));
      float a = gx + r * gh;
      a = fminf(fmaxf(a, -15.f), 15.f);
      float e2 = __expf(2.f * a);
      float n = (e2 - 1.f) * __frcp_rn(e2 + 1.f);
      float hold = s_h[row][i];
      s_h[row][i] = (1.f - z) * n + z * hold;
    }
    __syncthreads();
#pragma unroll
    for (int k = 0; k < 32; ++k) h[k] = s_h[row][k];
    __syncthreads();
  }
  for (int idx = tid; idx < 64 * 8; idx += 256) {
    int r = idx >> 3, c4 = idx & 7;
    float4 v = make_float4(s_h[r][c4 * 4], s_h[r][c4 * 4 + 1],
                           s_h[r][c4 * 4 + 2], s_h[r][c4 * 4 + 3]);
    *(float4*)&hout[(row0 + r) * 32 + c4 * 4] = v;
  }
}

// ---------------- graph build ----------------
__global__ void k_scatter(const int* __restrict__ ei, const float* __restrict__ ew,
                          float* __restrict__ A, int E) {
  int e = blockIdx.x * 256 + threadIdx.x;
  if (e < E) atomicAdd(&A[ei[e] * NN + ei[E + e]], ew[e]);
}

__global__ __launch_bounds__(256) void k_degree(const float* __restrict__ A,
                                                float* __restrict__ disq) {
  __shared__ float red[256];
  int row = blockIdx.x, tid = threadIdx.x;
  float s = 0.f;
  for (int j = tid; j < NN; j += 256) s += A[row * NN + j];
  red[tid] = s;
  __syncthreads();
  for (int off = 128; off > 0; off >>= 1) {
    if (tid < off) red[tid] += red[tid + off];
    __syncthreads();
  }
  if (tid == 0) disq[row] = 1.f / sqrtf(red[0]);
}

// ---- G = Lap*Lap^T with Lap computed on the fly from A and disq ----------
// lap(r,k) = delta(r,k) - disq[r]*A[r,k]*disq[k]. Upper-tri tiles + mirror.
__global__ __launch_bounds__(256) void k_mm_lap(const float* __restrict__ A,
                                                const float* __restrict__ disq,
                                                float* __restrict__ C) {
  if (blockIdx.x < blockIdx.y) return;
  __shared__ float As[32][68];
  __shared__ float Bs[32][68];
  __shared__ float Ts[64][65];
  int tid = threadIdx.x;
  int tx = tid & 15, ty = tid >> 4;
  int i0 = blockIdx.y * 64, j0 = blockIdx.x * 64;
  float acc[4][4];
#pragma unroll
  for (int a = 0; a < 4; ++a)
#pragma unroll
    for (int b = 0; b < 4; ++b) acc[a][b] = 0.f;
  int lrow = tid >> 3;
  int kk0 = (tid & 7) * 4;
  float drA0 = disq[i0 + lrow], drA1 = disq[i0 + lrow + 32];
  float drB0 = disq[j0 + lrow], drB1 = disq[j0 + lrow + 32];
  float4 pa0 = *(const float4*)&A[(long)(i0 + lrow) * NN + kk0];
  float4 pa1 = *(const float4*)&A[(long)(i0 + lrow + 32) * NN + kk0];
  float4 pb0 = *(const float4*)&A[(long)(j0 + lrow) * NN + kk0];
  float4 pb1 = *(const float4*)&A[(long)(j0 + lrow + 32) * NN + kk0];
  for (int k0 = 0; k0 < NN; k0 += 32) {
    float4 dq = *(const float4*)&disq[k0 + kk0];
    int kg = k0 + kk0;
#pragma unroll
    for (int e = 0; e < 4; ++e) {
      float dqe = (e == 0) ? dq.x : (e == 1) ? dq.y : (e == 2) ? dq.z : dq.w;
      float a0e = (e == 0) ? pa0.x : (e == 1) ? pa0.y : (e == 2) ? pa0.z : pa0.w;
      float a1e = (e == 0) ? pa1.x : (e == 1) ? pa1.y : (e == 2) ? pa1.z : pa1.w;
      float b0e = (e == 0) ? pb0.x : (e == 1) ? pb0.y : (e == 2) ? pb0.z : pb0.w;
      float b1e = (e == 0) ? pb1.x : (e == 1) ? pb1.y : (e == 2) ? pb1.z : pb1.w;
      float vA0 = -drA0 * a0e * dqe + ((i0 + lrow == kg + e) ? 1.f : 0.f);
      float vA1 = -drA1 * a1e * dqe + ((i0 + lrow + 32 == kg + e) ? 1.f : 0.f);
      float vB0 = -drB0 * b0e * dqe + ((j0 + lrow == kg + e) ? 1.f : 0.f);
      float vB1 = -drB1 * b1e * dqe + ((j0 + lrow + 32 == kg + e) ? 1.f : 0.f);
      As[kk0 + e][lrow] = vA0;
      As[kk0 + e][lrow + 32] = vA1;
      Bs[kk0 + e][lrow] = vB0;
      Bs[kk0 + e][lrow + 32] = vB1;
    }
    __syncthreads();
    if (k0 + 32 < NN) {
      pa0 = *(const float4*)&A[(long)(i0 + lrow) * NN + k0 + 32 + kk0];
      pa1 = *(const float4*)&A[(long)(i0 + lrow + 32) * NN + k0 + 32 + kk0];
      pb0 = *(const float4*)&A[(long)(j0 + lrow) * NN + k0 + 32 + kk0];
      pb1 = *(const float4*)&A[(long)(j0 + lrow + 32) * NN + k0 + 32 + kk0];
    }
#pragma unroll
    for (int kk = 0; kk < 32; ++kk) {
      float4 av = *(const float4*)&As[kk][ty * 4];
      float4 bv = *(const float4*)&Bs[kk][tx * 4];
      float aa[4] = {av.x, av.y, av.z, av.w};
      float bb[4] = {bv.x, bv.y, bv.z, bv.w};
#pragma unroll
      for (int a = 0; a < 4; ++a)
#pragma unroll
        for (int b = 0; b < 4; ++b) acc[a][b] += aa[a] * bb[b];
    }
    __syncthreads();
  }
#pragma unroll
  for (int a = 0; a < 4; ++a) {
    float4 v = make_float4(acc[a][0], acc[a][1], acc[a][2], acc[a][3]);
    *(float4*)&C[(long)(i0 + ty * 4 + a) * NN + j0 + tx * 4] = v;
  }
  if (i0 != j0) {
#pragma unroll
    for (int a = 0; a < 4; ++a)
#pragma unroll
      for (int b = 0; b < 4; ++b)
        Ts[tx * 4 + b][ty * 4 + a] = acc[a][b];
    __syncthreads();
    for (int idx = tid; idx < 64 * 16; idx += 256) {
      int r = idx >> 4, c4 = idx & 15;
      float4 v = make_float4(Ts[r][c4 * 4], Ts[r][c4 * 4 + 1],
                             Ts[r][c4 * 4 + 2], Ts[r][c4 * 4 + 3]);
      *(float4*)&C[(long)(j0 + r) * NN + i0 + c4 * 4] = v;
    }
  }
}

// ------ C = A*A^T (symmetric): upper-tri tiles + LDS-transposed mirror ----
__global__ __launch_bounds__(256) void k_mm_sym(const float* __restrict__ A,
                                                float* __restrict__ C) {
  if (blockIdx.x < blockIdx.y) return;
  __shared__ float As[32][68];
  __shared__ float Bs[32][68];
  __shared__ float Ts[64][65];
  int tid = threadIdx.x;
  int tx = tid & 15, ty = tid >> 4;
  int i0 = blockIdx.y * 64, j0 = blockIdx.x * 64;
  float acc[4][4];
#pragma unroll
  for (int a = 0; a < 4; ++a)
#pragma unroll
    for (int b = 0; b < 4; ++b) acc[a][b] = 0.f;
  int lrow = tid >> 3;
  int kk0 = (tid & 7) * 4;
  float4 pa0 = *(const float4*)&A[(long)(i0 + lrow) * NN + kk0];
  float4 pa1 = *(const float4*)&A[(long)(i0 + lrow + 32) * NN + kk0];
  float4 pb0 = *(const float4*)&A[(long)(j0 + lrow) * NN + kk0];
  float4 pb1 = *(const float4*)&A[(long)(j0 + lrow + 32) * NN + kk0];
  for (int k0 = 0; k0 < NN; k0 += 32) {
    As[kk0 + 0][lrow] = pa0.x; As[kk0 + 1][lrow] = pa0.y;
    As[kk0 + 2][lrow] = pa0.z; As[kk0 + 3][lrow] = pa0.w;
    As[kk0 + 0][lrow + 32] = pa1.x; As[kk0 + 1][lrow + 32] = pa1.y;
    As[kk0 + 2][lrow + 32] = pa1.z; As[kk0 + 3][lrow + 32] = pa1.w;
    Bs[kk0 + 0][lrow] = pb0.x; Bs[kk0 + 1][lrow] = pb0.y;
    Bs[kk0 + 2][lrow] = pb0.z; Bs[kk0 + 3][lrow] = pb0.w;
    Bs[kk0 + 0][lrow + 32] = pb1.x; Bs[kk0 + 1][lrow + 32] = pb1.y;
    Bs[kk0 + 2][lrow + 32] = pb1.z; Bs[kk0 + 3][lrow + 32] = pb1.w;
    __syncthreads();
    if (k0 + 32 < NN) {
      pa0 = *(const float4*)&A[(long)(i0 + lrow) * NN + k0 + 32 + kk0];
      pa1 = *(const float4*)&A[(long)(i0 + lrow + 32) * NN + k0 + 32 + kk0];
      pb0 = *(const float4*)&A[(long)(j0 + lrow) * NN + k0 + 32 + kk0];
      pb1 = *(const float4*)&A[(long)(j0 + lrow + 32) * NN + k0 + 32 + kk0];
    }
#pragma unroll
    for (int kk = 0; kk < 32; ++kk) {
      float4 av = *(const float4*)&As[kk][ty * 4];
      float4 bv = *(const float4*)&Bs[kk][tx * 4];
      float aa[4] = {av.x, av.y, av.z, av.w};
      float bb[4] = {bv.x, bv.y, bv.z, bv.w};
#pragma unroll
      for (int a = 0; a < 4; ++a)
#pragma unroll
        for (int b = 0; b < 4; ++b) acc[a][b] += aa[a] * bb[b];
    }
    __syncthreads();
  }
#pragma unroll
  for (int a = 0; a < 4; ++a) {
    float4 v = make_float4(acc[a][0], acc[a][1], acc[a][2], acc[a][3]);
    *(float4*)&C[(long)(i0 + ty * 4 + a) * NN + j0 + tx * 4] = v;
  }
  if (i0 != j0) {
#pragma unroll
    for (int a = 0; a < 4; ++a)
#pragma unroll
      for (int b = 0; b < 4; ++b)
        Ts[tx * 4 + b][ty * 4 + a] = acc[a][b];
    __syncthreads();
    for (int idx = tid; idx < 64 * 16; idx += 256) {
      int r = idx >> 4, c4 = idx & 15;
      float4 v = make_float4(Ts[r][c4 * 4], Ts[r][c4 * 4 + 1],
                             Ts[r][c4 * 4 + 2], Ts[r][c4 * 4 + 3]);
      *(float4*)&C[(long)(j0 + r) * NN + i0 + c4 * 4] = v;
    }
  }
}

// ---------------- subspace iteration ----------------
__global__ void k_q0(float* __restrict__ Q) {
  int i = blockIdx.x * 256 + threadIdx.x;
  if (i < NN * PP) {
    unsigned u = (unsigned)i * 2654435761u;
    u ^= u >> 16; u *= 2246822519u; u ^= u >> 13; u *= 3266489917u; u ^= u >> 16;
    Q[i] = (float)(u & 0xFFFFFF) * (1.f / 16777216.f) - 0.5f;
  }
}

__global__ __launch_bounds__(256) void k_spmm(const float* __restrict__ Gp,
                                              const float* __restrict__ Q,
                                              float* __restrict__ Zp) {
  __shared__ float Qs[64][49];
  __shared__ float Gs[16][65];
  int tid = threadIdx.x;
  int r = tid >> 4;
  int c0 = (tid & 15) * 3;
  int row0 = blockIdx.x * 16;
  int k0 = blockIdx.y * 256;
  float a0 = 0.f, a1 = 0.f, a2 = 0.f;
  for (int kt = 0; kt < 4; ++kt) {
    int kb = k0 + kt * 64;
    for (int idx = tid; idx < 64 * PP; idx += 256) {
      int qr = idx / PP, qc = idx % PP;
      Qs[qr][qc] = Q[(kb + qr) * PP + qc];
    }
    for (int idx = tid; idx < 16 * 64; idx += 256) {
      int gr = idx >> 6, gk = idx & 63;
      Gs[gr][gk] = Gp[(long)(row0 + gr) * NN + kb + gk];
    }
    __syncthreads();
#pragma unroll 4
    for (int kk = 0; kk < 64; ++kk) {
      float g = Gs[r][kk];
      a0 += g * Qs[kk][c0];
      a1 += g * Qs[kk][c0 + 1];
      a2 += g * Qs[kk][c0 + 2];
    }
    __syncthreads();
  }
  float* zp = Zp + (long)blockIdx.y * (NN * PP);
  zp[(row0 + r) * PP + c0] = a0;
  zp[(row0 + r) * PP + c0 + 1] = a1;
  zp[(row0 + r) * PP + c0 + 2] = a2;
}

// Sum 4 partials -> Z, per-block Gram partial Sp[blk].
__global__ __launch_bounds__(256) void k_gram(const float* __restrict__ Zp,
                                              float* __restrict__ Z,
                                              float* __restrict__ Sp) {
  __shared__ float Zs[32][49];
  int tid = threadIdx.x;
  int r0 = blockIdx.x * 32;
  for (int idx = tid; idx < 32 * PP; idx += 256) {
    int r = idx / PP, c = idx % PP;
    long g = (long)(r0 + r) * PP + c;
    float s = Zp[g] + Zp[g + NN * PP] + Zp[g + 2 * NN * PP] + Zp[g + 3 * NN * PP];
    Zs[r][c] = s;
    Z[g] = s;
  }
  __syncthreads();
  float* sp = Sp + blockIdx.x * (PP * PP);
  for (int cell = tid; cell < PP * PP; cell += 256) {
    int i = cell / PP, j = cell % PP;
    float a = 0.f;
#pragma unroll 8
    for (int r = 0; r < 32; ++r) a += Zs[r][i] * Zs[r][j];
    sp[cell] = a;
  }
}

__global__ __launch_bounds__(256) void k_tbuild(const float* __restrict__ Qa,
                                                const float* __restrict__ Zp,
                                                float* __restrict__ Tp) {
  __shared__ float Qs[32][49];
  __shared__ float Ys[32][49];
  int tid = threadIdx.x;
  int r0 = blockIdx.x * 32;
  for (int idx = tid; idx < 32 * PP; idx += 256) {
    int r = idx / PP, c = idx % PP;
    long g = (long)(r0 + r) * PP + c;
    Qs[r][c] = Qa[g];
    Ys[r][c] = Zp[g] + Zp[g + NN * PP] + Zp[g + 2 * NN * PP] + Zp[g + 3 * NN * PP];
  }
  __syncthreads();
  float* tp = Tp + blockIdx.x * (PP * PP);
  for (int cell = tid; cell < PP * PP; cell += 256) {
    int i = cell / PP, j = cell % PP;
    float a = 0.f;
#pragma unroll 8
    for (int r = 0; r < 32; ++r) a += Qs[r][i] * Ys[r][j];
    tp[cell] = a;
  }
}

// Fused CholQR apply: factorize summed Gram, rows solve y R = q in registers.
__global__ __launch_bounds__(256) void k_qr(const float* __restrict__ Sp,
                                            float* __restrict__ Q) {
  __shared__ float R[PP][PP + 1];
  __shared__ float rs[PP];
  __shared__ float idiag[PP];
  int tid = threadIdx.x;
  for (int idx = tid; idx < PP * PP; idx += 256) {
    float s = 0.f;
    for (int b = 0; b < 32; ++b) s += Sp[b * (PP * PP) + idx];
    R[idx / PP][idx % PP] = s;
  }
  __syncthreads();
  for (int j = 0; j < PP; ++j) {
    float d = R[j][j];
    float sq = sqrtf(d > 1e-30f ? d : 1e-30f);
    float invd = 1.f / sq;
    for (int c = j + tid; c < PP; c += 256)
      rs[c] = (c == j) ? sq : R[j][c] * invd;
    __syncthreads();
    int m = PP - 1 - j;
    for (int idx = tid; idx < m * m; idx += 256) {
      int i = j + 1 + idx / m, c = j + 1 + idx % m;
      R[i][c] -= rs[i] * rs[c];
    }
    for (int c = j + tid; c < PP; c += 256) R[j][c] = rs[c];
    __syncthreads();
  }
  if (tid < PP) idiag[tid] = 1.f / R[tid][tid];
  __syncthreads();
  int row = blockIdx.x * 256 + tid;
  float q[PP];
#pragma unroll
  for (int k = 0; k < PP; ++k) q[k] = Q[row * PP + k];
#pragma unroll
  for (int c = 0; c < PP; ++c) {
    float s = q[c];
#pragma unroll
    for (int k = 0; k < c; ++k) s -= q[k] * R[k][c];
    q[c] = s * idiag[c];
  }
#pragma unroll
  for (int k = 0; k < PP; ++k) Q[row * PP + k] = q[k];
}

// Shared-coefficient ping-pong cyclic Jacobi (2 barriers/round), 3 sweeps;
// top-10 select via wave-0 shfl butterfly.
__global__ __launch_bounds__(384) void k_jacobi(const float* __restrict__ Tp,
                                                float* __restrict__ Vsel,
                                                float* __restrict__ s10) {
  __shared__ float Ta[PP][PP + 1], Tb[PP][PP + 1];
  __shared__ float Va[PP][PP + 1], Vb[PP][PP + 1];
  __shared__ float w0[PP], w1[PP];
  __shared__ int j0a[PP], j1a[PP];
  __shared__ int selidx[10];
  int tid = threadIdx.x;
  for (int idx = tid; idx < PP * PP; idx += 384) {
    float s = 0.f;
    for (int b = 0; b < 32; ++b) s += Tp[b * (PP * PP) + idx];
    Tb[idx / PP][idx % PP] = s;
  }
  __syncthreads();
  for (int idx = tid; idx < PP * PP; idx += 384) {
    int i = idx / PP, j = idx % PP;
    Ta[i][j] = 0.5f * (Tb[i][j] + Tb[j][i]);
    Va[i][j] = (i == j) ? 1.f : 0.f;
  }
  __syncthreads();
  float (*Tc)[PP + 1] = Ta, (*Tn)[PP + 1] = Tb;
  float (*Vc)[PP + 1] = Va, (*Vn)[PP + 1] = Vb;
  int i_row = tid >> 3;
  int jb = (tid & 7) * 6;
  for (int sweep = 0; sweep < JSWEEPS; ++sweep) {
    for (int r = 0; r < PP - 1; ++r) {
      if (tid < 24) {
        int k = tid;
        int p = (k == 0) ? 0 : ((r + k - 1) % 47) + 1;
        int q = ((r + 46 - k) % 47) + 1;
        float app = Tc[p][p], aqq = Tc[q][q], apq = Tc[p][q];
        float c = 1.f, s = 0.f;
        if (fabsf(apq) > 1e-30f) {
          float tau = (aqq - app) / (2.f * apq);
          float den = fabsf(tau) + sqrtf(1.f + tau * tau);
          float tt = copysignf(1.f / den, tau);
          c = 1.f / sqrtf(1.f + tt * tt);
          s = tt * c;
        }
        j0a[p] = p; j1a[p] = q; w0[p] = c;  w1[p] = -s;
        j0a[q] = p; j1a[q] = q; w0[q] = s;  w1[q] = c;
      }
      __syncthreads();
      float wi0 = w0[i_row], wi1 = w1[i_row];
      int i0 = j0a[i_row], i1 = j1a[i_row];
      float tnew[6], vnew[6];
#pragma unroll
      for (int m = 0; m < 6; ++m) {
        int j = jb + m;
        float wj0 = w0[j], wj1 = w1[j];
        int a = j0a[j], b = j1a[j];
        tnew[m] = wi0 * (wj0 * Tc[i0][a] + wj1 * Tc[i0][b]) +
                  wi1 * (wj0 * Tc[i1][a] + wj1 * Tc[i1][b]);
        vnew[m] = wj0 * Vc[i_row][a] + wj1 * Vc[i_row][b];
      }
#pragma unroll
      for (int m = 0; m < 6; ++m) {
        Tn[i_row][jb + m] = tnew[m];
        Vn[i_row][jb + m] = vnew[m];
      }
      __syncthreads();
      float (*tt_)[PP + 1] = Tc; Tc = Tn; Tn = tt_;
      float (*vt_)[PP + 1] = Vc; Vc = Vn; Vn = vt_;
    }
  }
  if (tid < 64) {
    float v = (tid < PP) ? Tc[tid][tid] : -1e30f;
    for (int sel = 0; sel < 10; ++sel) {
      float bv = v; int bi = tid;
      for (int off = 32; off > 0; off >>= 1) {
        float ov = __shfl_xor(bv, off);
        int oi = __shfl_xor(bi, off);
        if (ov > bv || (ov == bv && oi < bi)) { bv = ov; bi = oi; }
      }
      if (tid == 0) { selidx[sel] = bi; s10[sel] = sqrtf(fmaxf(bv, 0.f)); }
      if (tid == bi) v = -1e30f;
    }
  }
  __syncthreads();
  for (int idx = tid; idx < PP * 10; idx += 384) {
    int j = idx / 10, i = idx % 10;
    Vsel[idx] = Vc[j][selidx[i]];
  }
}

// U10 = Qa * Vsel. grid 4 x 256.
__global__ __launch_bounds__(256) void k_u10(const float* __restrict__ Q,
                                             const float* __restrict__ Vsel,
                                             float* __restrict__ U10) {
  __shared__ float Vs[PP * 10];
  int tid = threadIdx.x;
  for (int idx = tid; idx < PP * 10; idx += 256) Vs[idx] = Vsel[idx];
  __syncthreads();
  int row = blockIdx.x * 256 + tid;
  float q[PP];
#pragma unroll
  for (int k = 0; k < PP; ++k) q[k] = Q[row * PP + k];
#pragma unroll
  for (int i = 0; i < 10; ++i) {
    float s = 0.f;
#pragma unroll
    for (int k = 0; k < PP; ++k) s += q[k] * Vs[k * 10 + i];
    U10[row * 10 + i] = s;
  }
}

// ---------------- conv layers ----------------
// P0 partials over 4 N-chunks: grid 256 (= 64 batches x 4 chunks).
__global__ __launch_bounds__(320) void k_p0(const float* __restrict__ h,
                                            const float* __restrict__ U10,
                                            float* __restrict__ Pp) {
  __shared__ float Hs[128][33];
  __shared__ float Us[128][10];
  int tid = threadIdx.x;
  int b = blockIdx.x >> 2, ch = blockIdx.x & 3;
  int i = tid / 32, kk = tid % 32;
  int base = ch * 256;
  float acc = 0.f;
  for (int t0 = 0; t0 < 256; t0 += 128) {
    for (int idx = tid; idx < 128 * 32; idx += 320) {
      int r = idx / 32, c = idx % 32;
      Hs[r][c] = h[(long)(b * NN + base + t0 + r) * 32 + c];
    }
    for (int idx = tid; idx < 1280; idx += 320)
      Us[idx / 10][idx % 10] = U10[(base + t0 + idx / 10) * 10 + idx % 10];
    __syncthreads();
#pragma unroll 8
    for (int r = 0; r < 128; ++r) acc += Us[r][i] * Hs[r][kk];
    __syncthreads();
  }
  Pp[(long)blockIdx.x * 320 + tid] = acc;
}

// Fold 4 P0 partials + P1 = s.*(P0 W) (redundant per block), then
// h += relu(U10 * P1); LAST also emits out = h_new @ lw + lb.
template <int LAST>
__global__ __launch_bounds__(256) void k_update(float* __restrict__ h,
                                                const float* __restrict__ U10,
                                                const float* __restrict__ Pp,
                                                const float* __restrict__ W,
                                                const float* __restrict__ s10,
                                                const float* __restrict__ lw,
                                                const float* __restrict__ lb,
                                                float* __restrict__ out) {
  __shared__ float P0s[10][32];
  __shared__ float P1s[10][32];
  __shared__ float Ws[32][32];
  __shared__ float Us[64][10];
  __shared__ float hl[64][33];
  int tid = threadIdx.x;
  int b = blockIdx.x, n0 = blockIdx.y * 64;
  for (int idx = tid; idx < 320; idx += 256) {
    long g = (long)b * 4 * 320 + idx;
    P0s[idx / 32][idx % 32] = Pp[g] + Pp[g + 320] + Pp[g + 640] + Pp[g + 960];
  }
  for (int idx = tid; idx < 1024; idx += 256) Ws[idx / 32][idx % 32] = W[idx];
  for (int idx = tid; idx < 640; idx += 256)
    Us[idx / 10][idx % 10] = U10[(n0 + idx / 10) * 10 + idx % 10];
  __syncthreads();
  for (int idx = tid; idx < 320; idx += 256) {
    int i = idx / 32, kk = idx % 32;
    float a = 0.f;
#pragma unroll
    for (int j = 0; j < 32; ++j) a += P0s[i][j] * Ws[j][kk];
    P1s[i][kk] = s10[i] * a;
  }
  __syncthreads();
  for (int idx = tid; idx < 2048; idx += 256) {
    int nl = idx / 32, k = idx % 32;
    float z = 0.f;
#pragma unroll
    for (int i = 0; i < 10; ++i) z += Us[nl][i] * P1s[i][k];
    long g = (long)(b * NN + n0 + nl) * 32 + k;
    float hn = h[g] + fmaxf(z, 0.f);
    if (LAST) hl[nl][k] = hn;
    else h[g] = hn;
  }
  if (LAST) {
    __syncthreads();
    for (int idx = tid; idx < 64 * 12; idx += 256) {
      int row = idx / 12, o = idx % 12;
      float s = lb[o];
#pragma unroll
      for (int j = 0; j < 32; ++j) s += hl[row][j] * lw[j * 12 + o];
      out[(long)(b * NN + n0 + row) * 12 + o] = s;
    }
  }
}

extern "C" void kernel_launch(void* const* d_in, const int* in_sizes, int n_in,
                              void* d_out, int out_size, void* d_ws, size_t ws_size,
                              hipStream_t stream) {
  const float* x    = (const float*)d_in[0];
  const int*   ei   = (const int*)d_in[1];
  const float* ew   = (const float*)d_in[2];
  const float* wih  = (const float*)d_in[3];
  const float* whh  = (const float*)d_in[4];
  const float* bih  = (const float*)d_in[5];
  const float* bhh  = (const float*)d_in[6];
  const float* convw = (const float*)d_in[7];
  const float* lw   = (const float*)d_in[8];
  const float* lb   = (const float*)d_in[9];
  float* out = (float*)d_out;
  float* ws  = (float*)d_ws;
  int E = in_sizes[1] / 2;

  float* h    = ws;                 // 2097152
  float* B1   = h + 2097152;        // 1048576
  float* B2   = B1 + 1048576;       // 1048576
  float* B3   = B2 + 1048576;       // 1048576
  float* Qa   = B3 + 1048576;       // 49152
  float* Qb   = Qa + 49152;         // 49152
  float* Zp   = Qb + 49152;         // 196608 (aliased as Pp in stage D)
  float* Sp   = Zp + 196608;        // 73728
  float* Tp   = Sp + 73728;         // 73728
  float* Vsel = Tp + 73728;         // 480
  float* s10  = Vsel + 480;         // 16
  float* U10  = s10 + 16;           // 10240
  float* disq = U10 + 10240;        // 1024
  float* Pp   = Zp;                 // 64*4*320 = 81920 (alias)

  // Stage A: GRU
  k_gru<<<1024, 256, 0, stream>>>(x, wih, whh, bih, bhh, h);

  // Stage B: A in B1, Laplacian fused into first matmul; B2=G, B3=G^32
  hipMemsetAsync(B1, 0, (size_t)1048576 * 4, stream);
  k_scatter<<<(E + 255) / 256, 256, 0, stream>>>(ei, ew, B1, E);
  k_degree<<<NN, 256, 0, stream>>>(B1, disq);
  k_mm_lap<<<dim3(16, 16), 256, 0, stream>>>(B1, disq, B2);  // G = Lap Lap^T
  k_mm_sym<<<dim3(16, 16), 256, 0, stream>>>(B2, B3);  // G^2
  k_mm_sym<<<dim3(16, 16), 256, 0, stream>>>(B3, B1);  // G^4 (A clobbered, ok)
  k_mm_sym<<<dim3(16, 16), 256, 0, stream>>>(B1, B3);  // G^8
  k_mm_sym<<<dim3(16, 16), 256, 0, stream>>>(B3, B1);  // G^16
  k_mm_sym<<<dim3(16, 16), 256, 0, stream>>>(B1, B3);  // G^32

  // Stage C: 6 applies of G^32 (=192 powers), CholQR after each
  k_q0<<<192, 256, 0, stream>>>(Qa);
  for (int it = 0; it < 6; ++it) {
    float* src = (it & 1) ? Qb : Qa;
    float* dst = (it & 1) ? Qa : Qb;
    k_spmm<<<dim3(64, 4), 256, 0, stream>>>(B3, src, Zp);
    k_gram<<<32, 256, 0, stream>>>(Zp, dst, Sp);
    k_qr<<<4, 256, 0, stream>>>(Sp, dst);
  }
  // final orthonormal basis in Qa

  // Rayleigh-Ritz with G (exact Jacobi, 3 sweeps — PINNED)
  k_spmm<<<dim3(64, 4), 256, 0, stream>>>(B2, Qa, Zp);
  k_tbuild<<<32, 256, 0, stream>>>(Qa, Zp, Tp);
  k_jacobi<<<1, 384, 0, stream>>>(Tp, Vsel, s10);
  k_u10<<<4, 256, 0, stream>>>(Qa, Vsel, U10);

  // Stage D: conv layers (256-blk chunked projection, fold in update)
  for (int l = 0; l < 3; ++l) {
    k_p0<<<256, 320, 0, stream>>>(h, U10, Pp);
    if (l < 2)
      k_update<0><<<dim3(64, 16), 256, 0, stream>>>(h, U10, Pp, convw + l * 1024,
                                                    s10, lw, lb, out);
    else
      k_update<1><<<dim3(64, 16), 256, 0, stream>>>(h, U10, Pp, convw + l * 1024,
                                                    s10, lw, lb, out);
  }
}

// Round 12
// 1129.670 us; speedup vs baseline: 1.2914x; 1.0774x over previous
//
#include <hip/hip_runtime.h>
#include <math.h>

// SpectralGCN: normalized Laplacian (fused into first matmul) -> G powers to
// G^32 (split-K full-grid matmuls + fold) -> 6x subspace applies with CholQR
// -> Rayleigh-Ritz Jacobi (3 sweeps PINNED; 1-barrier/round pipelined
// lookahead coefficients) -> GRU -> 3 conv layers -> fused linear out.
// Matmul partial buffers alias h: GRU launches AFTER the spectral path.
// Sizes: B=64, N=1024, F=8, T=12, H=32, K=10, OUT=12.

#define NN 1024
#define PP 48
#define JSWEEPS 3
#define NROUNDS (JSWEEPS * (PP - 1))

// ---------------- GRU ----------------
// 4 waves/block, 64 rows/block; wave w computes channels [8w, 8w+8).
__global__ __launch_bounds__(256) void k_gru(
    const float* __restrict__ x, const float* __restrict__ wih,
    const float* __restrict__ whh, const float* __restrict__ bih,
    const float* __restrict__ bhh, float* __restrict__ hout) {
  __shared__ float s_x[64][97];
  __shared__ float s_h[64][33];
  int tid = threadIdx.x;
  int row = tid & 63;
  int i_base = __builtin_amdgcn_readfirstlane((tid >> 6) * 8);
  long row0 = (long)blockIdx.x * 64;

  for (int i = tid; i < 64 * 24; i += 256) {
    int r = i / 24, c = i % 24;
    float4 v = *(const float4*)&x[(row0 + r) * 96 + c * 4];
    s_x[r][c * 4 + 0] = v.x; s_x[r][c * 4 + 1] = v.y;
    s_x[r][c * 4 + 2] = v.z; s_x[r][c * 4 + 3] = v.w;
  }
  for (int i = tid; i < 64 * 32; i += 256) s_h[i / 32][i % 32] = 0.f;
  __syncthreads();

  float h[32];
#pragma unroll
  for (int k = 0; k < 32; ++k) h[k] = 0.f;

  for (int t = 0; t < 12; ++t) {
    float x8[8];
#pragma unroll
    for (int f = 0; f < 8; ++f) x8[f] = s_x[row][f * 12 + t];
    for (int ii = 0; ii < 8; ++ii) {
      int i = i_base + ii;                  // wave-uniform
      float ar = bih[i] + bhh[i];
      float az = bih[32 + i] + bhh[32 + i];
      float gx = bih[64 + i];
      float gh = bhh[64 + i];
#pragma unroll
      for (int f = 0; f < 8; ++f) {
        ar += x8[f] * wih[i * 8 + f];
        az += x8[f] * wih[(32 + i) * 8 + f];
        gx += x8[f] * wih[(64 + i) * 8 + f];
      }
#pragma unroll
      for (int k = 0; k < 32; ++k) {
        ar += h[k] * whh[i * 32 + k];
        az += h[k] * whh[(32 + i) * 32 + k];
        gh += h[k] * whh[(64 + i) * 32 + k];
      }
      ar = fminf(fmaxf(ar, -30.f), 30.f);
      az = fminf(fmaxf(az, -30.f), 30.f);
      float r = __frcp_rn(1.f + __expf(-ar));
      float z = __frcp_rn(1.f + __expf(-az));
      float a = gx + r * gh;
      a = fminf(fmaxf(a, -15.f), 15.f);
      float e2 = __expf(2.f * a);
      float n = (e2 - 1.f) * __frcp_rn(e2 + 1.f);
      float hold = s_h[row][i];
      s_h[row][i] = (1.f - z) * n + z * hold;
    }
    __syncthreads();
#pragma unroll
    for (int k = 0; k < 32; ++k) h[k] = s_h[row][k];
    __syncthreads();
  }
  for (int idx = tid; idx < 64 * 8; idx += 256) {
    int r = idx >> 3, c4 = idx & 7;
    float4 v = make_float4(s_h[r][c4 * 4], s_h[r][c4 * 4 + 1],
                           s_h[r][c4 * 4 + 2], s_h[r][c4 * 4 + 3]);
    *(float4*)&hout[(row0 + r) * 32 + c4 * 4] = v;
  }
}

// ---------------- graph build ----------------
__global__ void k_scatter(const int* __restrict__ ei, const float* __restrict__ ew,
                          float* __restrict__ A, int E) {
  int e = blockIdx.x * 256 + threadIdx.x;
  if (e < E) atomicAdd(&A[ei[e] * NN + ei[E + e]], ew[e]);
}

__global__ __launch_bounds__(256) void k_degree(const float* __restrict__ A,
                                                float* __restrict__ disq) {
  __shared__ float red[256];
  int row = blockIdx.x, tid = threadIdx.x;
  float s = 0.f;
  for (int j = tid; j < NN; j += 256) s += A[row * NN + j];
  red[tid] = s;
  __syncthreads();
  for (int off = 128; off > 0; off >>= 1) {
    if (tid < off) red[tid] += red[tid + off];
    __syncthreads();
  }
  if (tid == 0) disq[row] = 1.f / sqrtf(red[0]);
}

// ---- split-K symmetric matmul: Cp[z] = (rows x Khalf_z) partial of M*M^T --
// LAP=1: M = Lap computed on the fly from A,disq; LAP=0: M = A.
// grid (16,16,2): full tile grid (no tri skip), z = K half. 512 blocks.
template <int LAP>
__global__ __launch_bounds__(256) void k_mmsplit(const float* __restrict__ A,
                                                 const float* __restrict__ disq,
                                                 float* __restrict__ Cp) {
  __shared__ float As[32][68];
  __shared__ float Bs[32][68];
  int tid = threadIdx.x;
  int tx = tid & 15, ty = tid >> 4;
  int i0 = blockIdx.y * 64, j0 = blockIdx.x * 64;
  int kbase = blockIdx.z * 512;
  float acc[4][4];
#pragma unroll
  for (int a = 0; a < 4; ++a)
#pragma unroll
    for (int b = 0; b < 4; ++b) acc[a][b] = 0.f;
  int lrow = tid >> 3;
  int kk0 = (tid & 7) * 4;
  float drA0 = 0.f, drA1 = 0.f, drB0 = 0.f, drB1 = 0.f;
  if (LAP) {
    drA0 = disq[i0 + lrow]; drA1 = disq[i0 + lrow + 32];
    drB0 = disq[j0 + lrow]; drB1 = disq[j0 + lrow + 32];
  }
  float4 pa0 = *(const float4*)&A[(long)(i0 + lrow) * NN + kbase + kk0];
  float4 pa1 = *(const float4*)&A[(long)(i0 + lrow + 32) * NN + kbase + kk0];
  float4 pb0 = *(const float4*)&A[(long)(j0 + lrow) * NN + kbase + kk0];
  float4 pb1 = *(const float4*)&A[(long)(j0 + lrow + 32) * NN + kbase + kk0];
  for (int k0 = kbase; k0 < kbase + 512; k0 += 32) {
    if (LAP) {
      float4 dq = *(const float4*)&disq[k0 + kk0];
      int kg = k0 + kk0;
#pragma unroll
      for (int e = 0; e < 4; ++e) {
        float dqe = (e == 0) ? dq.x : (e == 1) ? dq.y : (e == 2) ? dq.z : dq.w;
        float a0e = (e == 0) ? pa0.x : (e == 1) ? pa0.y : (e == 2) ? pa0.z : pa0.w;
        float a1e = (e == 0) ? pa1.x : (e == 1) ? pa1.y : (e == 2) ? pa1.z : pa1.w;
        float b0e = (e == 0) ? pb0.x : (e == 1) ? pb0.y : (e == 2) ? pb0.z : pb0.w;
        float b1e = (e == 0) ? pb1.x : (e == 1) ? pb1.y : (e == 2) ? pb1.z : pb1.w;
        As[kk0 + e][lrow]      = -drA0 * a0e * dqe + ((i0 + lrow == kg + e) ? 1.f : 0.f);
        As[kk0 + e][lrow + 32] = -drA1 * a1e * dqe + ((i0 + lrow + 32 == kg + e) ? 1.f : 0.f);
        Bs[kk0 + e][lrow]      = -drB0 * b0e * dqe + ((j0 + lrow == kg + e) ? 1.f : 0.f);
        Bs[kk0 + e][lrow + 32] = -drB1 * b1e * dqe + ((j0 + lrow + 32 == kg + e) ? 1.f : 0.f);
      }
    } else {
      As[kk0 + 0][lrow] = pa0.x; As[kk0 + 1][lrow] = pa0.y;
      As[kk0 + 2][lrow] = pa0.z; As[kk0 + 3][lrow] = pa0.w;
      As[kk0 + 0][lrow + 32] = pa1.x; As[kk0 + 1][lrow + 32] = pa1.y;
      As[kk0 + 2][lrow + 32] = pa1.z; As[kk0 + 3][lrow + 32] = pa1.w;
      Bs[kk0 + 0][lrow] = pb0.x; Bs[kk0 + 1][lrow] = pb0.y;
      Bs[kk0 + 2][lrow] = pb0.z; Bs[kk0 + 3][lrow] = pb0.w;
      Bs[kk0 + 0][lrow + 32] = pb1.x; Bs[kk0 + 1][lrow + 32] = pb1.y;
      Bs[kk0 + 2][lrow + 32] = pb1.z; Bs[kk0 + 3][lrow + 32] = pb1.w;
    }
    __syncthreads();
    if (k0 + 32 < kbase + 512) {
      pa0 = *(const float4*)&A[(long)(i0 + lrow) * NN + k0 + 32 + kk0];
      pa1 = *(const float4*)&A[(long)(i0 + lrow + 32) * NN + k0 + 32 + kk0];
      pb0 = *(const float4*)&A[(long)(j0 + lrow) * NN + k0 + 32 + kk0];
      pb1 = *(const float4*)&A[(long)(j0 + lrow + 32) * NN + k0 + 32 + kk0];
    }
#pragma unroll
    for (int kk = 0; kk < 32; ++kk) {
      float4 av = *(const float4*)&As[kk][ty * 4];
      float4 bv = *(const float4*)&Bs[kk][tx * 4];
      float aa[4] = {av.x, av.y, av.z, av.w};
      float bb[4] = {bv.x, bv.y, bv.z, bv.w};
#pragma unroll
      for (int a = 0; a < 4; ++a)
#pragma unroll
        for (int b = 0; b < 4; ++b) acc[a][b] += aa[a] * bb[b];
    }
    __syncthreads();
  }
  float* cp = Cp + (long)blockIdx.z * (NN * NN);
#pragma unroll
  for (int a = 0; a < 4; ++a) {
    float4 v = make_float4(acc[a][0], acc[a][1], acc[a][2], acc[a][3]);
    *(float4*)&cp[(long)(i0 + ty * 4 + a) * NN + j0 + tx * 4] = v;
  }
}

// C = Cp[0] + Cp[1] (deterministic fold). grid 1024 x 256, float4/thread.
__global__ __launch_bounds__(256) void k_fold(const float* __restrict__ Cp,
                                              float* __restrict__ C) {
  int i = (blockIdx.x * 256 + threadIdx.x) * 4;
  float4 a = *(const float4*)&Cp[i];
  float4 b = *(const float4*)&Cp[i + NN * NN];
  float4 v = make_float4(a.x + b.x, a.y + b.y, a.z + b.z, a.w + b.w);
  *(float4*)&C[i] = v;
}

// ---------------- subspace iteration ----------------
__global__ void k_q0(float* __restrict__ Q) {
  int i = blockIdx.x * 256 + threadIdx.x;
  if (i < NN * PP) {
    unsigned u = (unsigned)i * 2654435761u;
    u ^= u >> 16; u *= 2246822519u; u ^= u >> 13; u *= 3266489917u; u ^= u >> 16;
    Q[i] = (float)(u & 0xFFFFFF) * (1.f / 16777216.f) - 0.5f;
  }
}

__global__ __launch_bounds__(256) void k_spmm(const float* __restrict__ Gp,
                                              const float* __restrict__ Q,
                                              float* __restrict__ Zp) {
  __shared__ float Qs[64][49];
  __shared__ float Gs[16][65];
  int tid = threadIdx.x;
  int r = tid >> 4;
  int c0 = (tid & 15) * 3;
  int row0 = blockIdx.x * 16;
  int k0 = blockIdx.y * 256;
  float a0 = 0.f, a1 = 0.f, a2 = 0.f;
  for (int kt = 0; kt < 4; ++kt) {
    int kb = k0 + kt * 64;
    for (int idx = tid; idx < 64 * PP; idx += 256) {
      int qr = idx / PP, qc = idx % PP;
      Qs[qr][qc] = Q[(kb + qr) * PP + qc];
    }
    for (int idx = tid; idx < 16 * 64; idx += 256) {
      int gr = idx >> 6, gk = idx & 63;
      Gs[gr][gk] = Gp[(long)(row0 + gr) * NN + kb + gk];
    }
    __syncthreads();
#pragma unroll 4
    for (int kk = 0; kk < 64; ++kk) {
      float g = Gs[r][kk];
      a0 += g * Qs[kk][c0];
      a1 += g * Qs[kk][c0 + 1];
      a2 += g * Qs[kk][c0 + 2];
    }
    __syncthreads();
  }
  float* zp = Zp + (long)blockIdx.y * (NN * PP);
  zp[(row0 + r) * PP + c0] = a0;
  zp[(row0 + r) * PP + c0 + 1] = a1;
  zp[(row0 + r) * PP + c0 + 2] = a2;
}

// Sum 4 partials -> Z, per-block Gram partial Sp[blk].
__global__ __launch_bounds__(256) void k_gram(const float* __restrict__ Zp,
                                              float* __restrict__ Z,
                                              float* __restrict__ Sp) {
  __shared__ float Zs[32][49];
  int tid = threadIdx.x;
  int r0 = blockIdx.x * 32;
  for (int idx = tid; idx < 32 * PP; idx += 256) {
    int r = idx / PP, c = idx % PP;
    long g = (long)(r0 + r) * PP + c;
    float s = Zp[g] + Zp[g + NN * PP] + Zp[g + 2 * NN * PP] + Zp[g + 3 * NN * PP];
    Zs[r][c] = s;
    Z[g] = s;
  }
  __syncthreads();
  float* sp = Sp + blockIdx.x * (PP * PP);
  for (int cell = tid; cell < PP * PP; cell += 256) {
    int i = cell / PP, j = cell % PP;
    float a = 0.f;
#pragma unroll 8
    for (int r = 0; r < 32; ++r) a += Zs[r][i] * Zs[r][j];
    sp[cell] = a;
  }
}

__global__ __launch_bounds__(256) void k_tbuild(const float* __restrict__ Qa,
                                                const float* __restrict__ Zp,
                                                float* __restrict__ Tp) {
  __shared__ float Qs[32][49];
  __shared__ float Ys[32][49];
  int tid = threadIdx.x;
  int r0 = blockIdx.x * 32;
  for (int idx = tid; idx < 32 * PP; idx += 256) {
    int r = idx / PP, c = idx % PP;
    long g = (long)(r0 + r) * PP + c;
    Qs[r][c] = Qa[g];
    Ys[r][c] = Zp[g] + Zp[g + NN * PP] + Zp[g + 2 * NN * PP] + Zp[g + 3 * NN * PP];
  }
  __syncthreads();
  float* tp = Tp + blockIdx.x * (PP * PP);
  for (int cell = tid; cell < PP * PP; cell += 256) {
    int i = cell / PP, j = cell % PP;
    float a = 0.f;
#pragma unroll 8
    for (int r = 0; r < 32; ++r) a += Qs[r][i] * Ys[r][j];
    tp[cell] = a;
  }
}

// Fused CholQR apply: factorize summed Gram, rows solve y R = q in registers.
__global__ __launch_bounds__(256) void k_qr(const float* __restrict__ Sp,
                                            float* __restrict__ Q) {
  __shared__ float R[PP][PP + 1];
  __shared__ float rs[PP];
  __shared__ float idiag[PP];
  int tid = threadIdx.x;
  for (int idx = tid; idx < PP * PP; idx += 256) {
    float s = 0.f;
    for (int b = 0; b < 32; ++b) s += Sp[b * (PP * PP) + idx];
    R[idx / PP][idx % PP] = s;
  }
  __syncthreads();
  for (int j = 0; j < PP; ++j) {
    float d = R[j][j];
    float sq = sqrtf(d > 1e-30f ? d : 1e-30f);
    float invd = 1.f / sq;
    for (int c = j + tid; c < PP; c += 256)
      rs[c] = (c == j) ? sq : R[j][c] * invd;
    __syncthreads();
    int m = PP - 1 - j;
    for (int idx = tid; idx < m * m; idx += 256) {
      int i = j + 1 + idx / m, c = j + 1 + idx % m;
      R[i][c] -= rs[i] * rs[c];
    }
    for (int c = j + tid; c < PP; c += 256) R[j][c] = rs[c];
    __syncthreads();
  }
  if (tid < PP) idiag[tid] = 1.f / R[tid][tid];
  __syncthreads();
  int row = blockIdx.x * 256 + tid;
  float q[PP];
#pragma unroll
  for (int k = 0; k < PP; ++k) q[k] = Q[row * PP + k];
#pragma unroll
  for (int c = 0; c < PP; ++c) {
    float s = q[c];
#pragma unroll
    for (int k = 0; k < c; ++k) s -= q[k] * R[k][c];
    q[c] = s * idiag[c];
  }
#pragma unroll
  for (int k = 0; k < PP; ++k) Q[row * PP + k] = q[k];
}

// Pipelined-lookahead cyclic Jacobi: 1 barrier/round. Waves 0-5 (384 thr)
// apply round R's rotations (coeff buffer cur); wave 6 lanes 0-23 compute
// round R+1's coefficients from the SAME pre-round state via the identical
// 4-read rotation transform (algebraically the same values). 3 sweeps PINNED.
__global__ __launch_bounds__(448) void k_jacobi(const float* __restrict__ Tp,
                                                float* __restrict__ Vsel,
                                                float* __restrict__ s10) {
  __shared__ float Ta[PP][PP + 1], Tb[PP][PP + 1];
  __shared__ float Va[PP][PP + 1], Vb[PP][PP + 1];
  __shared__ float w0b[2][PP], w1b[2][PP];
  __shared__ int j0b[2][PP], j1b[2][PP];
  __shared__ int selidx[10];
  int tid = threadIdx.x;
  for (int idx = tid; idx < PP * PP; idx += 448) {
    float s = 0.f;
    for (int b = 0; b < 32; ++b) s += Tp[b * (PP * PP) + idx];
    Tb[idx / PP][idx % PP] = s;
  }
  __syncthreads();
  for (int idx = tid; idx < PP * PP; idx += 448) {
    int i = idx / PP, j = idx % PP;
    Ta[i][j] = 0.5f * (Tb[i][j] + Tb[j][i]);
    Va[i][j] = (i == j) ? 1.f : 0.f;
  }
  if (tid < PP) {  // identity mapping in coeff buffer 0
    j0b[0][tid] = tid; j1b[0][tid] = tid;
    w0b[0][tid] = 1.f; w1b[0][tid] = 0.f;
  }
  __syncthreads();
  float (*Tc)[PP + 1] = Ta, (*Tn)[PP + 1] = Tb;
  float (*Vc)[PP + 1] = Va, (*Vn)[PP + 1] = Vb;

  // coefficient computation for round rr into buffer nxt, viewing Tc through
  // the rotations stored in buffer cur (identity => direct reads).
  auto coeff_phase = [&](int rr, int cur, int nxt,
                         float (*Tcur)[PP + 1]) {
    int k = tid - 384;
    int P = (k == 0) ? 0 : ((rr + k - 1) % 47) + 1;
    int Q = ((rr + 46 - k) % 47) + 1;
    int P0 = j0b[cur][P], P1 = j1b[cur][P];
    float Pw0 = w0b[cur][P], Pw1 = w1b[cur][P];
    int Q0 = j0b[cur][Q], Q1 = j1b[cur][Q];
    float Qw0 = w0b[cur][Q], Qw1 = w1b[cur][Q];
    float app = Pw0 * (Pw0 * Tcur[P0][P0] + Pw1 * Tcur[P0][P1]) +
                Pw1 * (Pw0 * Tcur[P1][P0] + Pw1 * Tcur[P1][P1]);
    float apq = Pw0 * (Qw0 * Tcur[P0][Q0] + Qw1 * Tcur[P0][Q1]) +
                Pw1 * (Qw0 * Tcur[P1][Q0] + Qw1 * Tcur[P1][Q1]);
    float aqq = Qw0 * (Qw0 * Tcur[Q0][Q0] + Qw1 * Tcur[Q0][Q1]) +
                Qw1 * (Qw0 * Tcur[Q1][Q0] + Qw1 * Tcur[Q1][Q1]);
    float c = 1.f, s = 0.f;
    if (fabsf(apq) > 1e-30f) {
      float tau = (aqq - app) / (2.f * apq);
      float den = fabsf(tau) + sqrtf(1.f + tau * tau);
      float tt = copysignf(1.f / den, tau);
      c = 1.f / sqrtf(1.f + tt * tt);
      s = tt * c;
    }
    j0b[nxt][P] = P; j1b[nxt][P] = Q; w0b[nxt][P] = c;  w1b[nxt][P] = -s;
    j0b[nxt][Q] = P; j1b[nxt][Q] = Q; w0b[nxt][Q] = s;  w1b[nxt][Q] = c;
  };

  // prologue: coefficients for round 0 into buffer 1 (identity view)
  if (tid >= 384 && tid < 408) coeff_phase(0, 0, 1, Tc);
  __syncthreads();

  int cur = 1;
  int i_row = tid >> 3;          // valid for tid<384
  int jb = (tid & 7) * 6;
  for (int R = 0; R < NROUNDS; ++R) {
    if (tid < 384) {
      float wi0 = w0b[cur][i_row], wi1 = w1b[cur][i_row];
      int i0 = j0b[cur][i_row], i1 = j1b[cur][i_row];
      float tnew[6], vnew[6];
#pragma unroll
      for (int m = 0; m < 6; ++m) {
        int j = jb + m;
        float wj0 = w0b[cur][j], wj1 = w1b[cur][j];
        int a = j0b[cur][j], b = j1b[cur][j];
        tnew[m] = wi0 * (wj0 * Tc[i0][a] + wj1 * Tc[i0][b]) +
                  wi1 * (wj0 * Tc[i1][a] + wj1 * Tc[i1][b]);
        vnew[m] = wj0 * Vc[i_row][a] + wj1 * Vc[i_row][b];
      }
#pragma unroll
      for (int m = 0; m < 6; ++m) {
        Tn[i_row][jb + m] = tnew[m];
        Vn[i_row][jb + m] = vnew[m];
      }
    } else if (tid < 408 && R + 1 < NROUNDS) {
      coeff_phase((R + 1) % 47, cur, cur ^ 1, Tc);
    }
    __syncthreads();
    float (*tt_)[PP + 1] = Tc; Tc = Tn; Tn = tt_;
    float (*vt_)[PP + 1] = Vc; Vc = Vn; Vn = vt_;
    cur ^= 1;
  }

  if (tid < 64) {
    float v = (tid < PP) ? Tc[tid][tid] : -1e30f;
    for (int sel = 0; sel < 10; ++sel) {
      float bv = v; int bi = tid;
      for (int off = 32; off > 0; off >>= 1) {
        float ov = __shfl_xor(bv, off);
        int oi = __shfl_xor(bi, off);
        if (ov > bv || (ov == bv && oi < bi)) { bv = ov; bi = oi; }
      }
      if (tid == 0) { selidx[sel] = bi; s10[sel] = sqrtf(fmaxf(bv, 0.f)); }
      if (tid == bi) v = -1e30f;
    }
  }
  __syncthreads();
  for (int idx = tid; idx < PP * 10; idx += 448) {
    int j = idx / 10, i = idx % 10;
    Vsel[idx] = Vc[j][selidx[i]];
  }
}

// U10 = Qa * Vsel. grid 4 x 256.
__global__ __launch_bounds__(256) void k_u10(const float* __restrict__ Q,
                                             const float* __restrict__ Vsel,
                                             float* __restrict__ U10) {
  __shared__ float Vs[PP * 10];
  int tid = threadIdx.x;
  for (int idx = tid; idx < PP * 10; idx += 256) Vs[idx] = Vsel[idx];
  __syncthreads();
  int row = blockIdx.x * 256 + tid;
  float q[PP];
#pragma unroll
  for (int k = 0; k < PP; ++k) q[k] = Q[row * PP + k];
#pragma unroll
  for (int i = 0; i < 10; ++i) {
    float s = 0.f;
#pragma unroll
    for (int k = 0; k < PP; ++k) s += q[k] * Vs[k * 10 + i];
    U10[row * 10 + i] = s;
  }
}

// ---------------- conv layers ----------------
// P0 partials over 4 N-chunks: grid 256 (= 64 batches x 4 chunks).
__global__ __launch_bounds__(320) void k_p0(const float* __restrict__ h,
                                            const float* __restrict__ U10,
                                            float* __restrict__ Pp) {
  __shared__ float Hs[128][33];
  __shared__ float Us[128][10];
  int tid = threadIdx.x;
  int b = blockIdx.x >> 2, ch = blockIdx.x & 3;
  int i = tid / 32, kk = tid % 32;
  int base = ch * 256;
  float acc = 0.f;
  for (int t0 = 0; t0 < 256; t0 += 128) {
    for (int idx = tid; idx < 128 * 32; idx += 320) {
      int r = idx / 32, c = idx % 32;
      Hs[r][c] = h[(long)(b * NN + base + t0 + r) * 32 + c];
    }
    for (int idx = tid; idx < 1280; idx += 320)
      Us[idx / 10][idx % 10] = U10[(base + t0 + idx / 10) * 10 + idx % 10];
    __syncthreads();
#pragma unroll 8
    for (int r = 0; r < 128; ++r) acc += Us[r][i] * Hs[r][kk];
    __syncthreads();
  }
  Pp[(long)blockIdx.x * 320 + tid] = acc;
}

// Fold 4 P0 partials + P1 = s.*(P0 W) (redundant per block), then
// h += relu(U10 * P1); LAST also emits out = h_new @ lw + lb.
template <int LAST>
__global__ __launch_bounds__(256) void k_update(float* __restrict__ h,
                                                const float* __restrict__ U10,
                                                const float* __restrict__ Pp,
                                                const float* __restrict__ W,
                                                const float* __restrict__ s10,
                                                const float* __restrict__ lw,
                                                const float* __restrict__ lb,
                                                float* __restrict__ out) {
  __shared__ float P0s[10][32];
  __shared__ float P1s[10][32];
  __shared__ float Ws[32][32];
  __shared__ float Us[64][10];
  __shared__ float hl[64][33];
  int tid = threadIdx.x;
  int b = blockIdx.x, n0 = blockIdx.y * 64;
  for (int idx = tid; idx < 320; idx += 256) {
    long g = (long)b * 4 * 320 + idx;
    P0s[idx / 32][idx % 32] = Pp[g] + Pp[g + 320] + Pp[g + 640] + Pp[g + 960];
  }
  for (int idx = tid; idx < 1024; idx += 256) Ws[idx / 32][idx % 32] = W[idx];
  for (int idx = tid; idx < 640; idx += 256)
    Us[idx / 10][idx % 10] = U10[(n0 + idx / 10) * 10 + idx % 10];
  __syncthreads();
  for (int idx = tid; idx < 320; idx += 256) {
    int i = idx / 32, kk = idx % 32;
    float a = 0.f;
#pragma unroll
    for (int j = 0; j < 32; ++j) a += P0s[i][j] * Ws[j][kk];
    P1s[i][kk] = s10[i] * a;
  }
  __syncthreads();
  for (int idx = tid; idx < 2048; idx += 256) {
    int nl = idx / 32, k = idx % 32;
    float z = 0.f;
#pragma unroll
    for (int i = 0; i < 10; ++i) z += Us[nl][i] * P1s[i][k];
    long g = (long)(b * NN + n0 + nl) * 32 + k;
    float hn = h[g] + fmaxf(z, 0.f);
    if (LAST) hl[nl][k] = hn;
    else h[g] = hn;
  }
  if (LAST) {
    __syncthreads();
    for (int idx = tid; idx < 64 * 12; idx += 256) {
      int row = idx / 12, o = idx % 12;
      float s = lb[o];
#pragma unroll
      for (int j = 0; j < 32; ++j) s += hl[row][j] * lw[j * 12 + o];
      out[(long)(b * NN + n0 + row) * 12 + o] = s;
    }
  }
}

extern "C" void kernel_launch(void* const* d_in, const int* in_sizes, int n_in,
                              void* d_out, int out_size, void* d_ws, size_t ws_size,
                              hipStream_t stream) {
  const float* x    = (const float*)d_in[0];
  const int*   ei   = (const int*)d_in[1];
  const float* ew   = (const float*)d_in[2];
  const float* wih  = (const float*)d_in[3];
  const float* whh  = (const float*)d_in[4];
  const float* bih  = (const float*)d_in[5];
  const float* bhh  = (const float*)d_in[6];
  const float* convw = (const float*)d_in[7];
  const float* lw   = (const float*)d_in[8];
  const float* lb   = (const float*)d_in[9];
  float* out = (float*)d_out;
  float* ws  = (float*)d_ws;
  int E = in_sizes[1] / 2;

  float* h    = ws;                 // 2097152 (aliased as Cp during stage B)
  float* B1   = h + 2097152;        // 1048576
  float* B2   = B1 + 1048576;       // 1048576
  float* B3   = B2 + 1048576;       // 1048576
  float* Qa   = B3 + 1048576;       // 49152
  float* Qb   = Qa + 49152;         // 49152
  float* Zp   = Qb + 49152;         // 196608 (aliased as Pp in stage D)
  float* Sp   = Zp + 196608;        // 73728
  float* Tp   = Sp + 73728;         // 73728
  float* Vsel = Tp + 73728;         // 480
  float* s10  = Vsel + 480;         // 16
  float* U10  = s10 + 16;           // 10240
  float* disq = U10 + 10240;        // 1024
  float* Pp   = Zp;                 // alias
  float* Cp   = h;                  // 2x 1048576 split-K partials (alias)

  // Stage B first (Cp aliases h; GRU comes after the spectral path)
  hipMemsetAsync(B1, 0, (size_t)1048576 * 4, stream);
  k_scatter<<<(E + 255) / 256, 256, 0, stream>>>(ei, ew, B1, E);
  k_degree<<<NN, 256, 0, stream>>>(B1, disq);
  k_mmsplit<1><<<dim3(16, 16, 2), 256, 0, stream>>>(B1, disq, Cp);
  k_fold<<<1024, 256, 0, stream>>>(Cp, B2);                       // G
  k_mmsplit<0><<<dim3(16, 16, 2), 256, 0, stream>>>(B2, disq, Cp);
  k_fold<<<1024, 256, 0, stream>>>(Cp, B3);                       // G^2
  k_mmsplit<0><<<dim3(16, 16, 2), 256, 0, stream>>>(B3, disq, Cp);
  k_fold<<<1024, 256, 0, stream>>>(Cp, B1);                       // G^4
  k_mmsplit<0><<<dim3(16, 16, 2), 256, 0, stream>>>(B1, disq, Cp);
  k_fold<<<1024, 256, 0, stream>>>(Cp, B3);                       // G^8
  k_mmsplit<0><<<dim3(16, 16, 2), 256, 0, stream>>>(B3, disq, Cp);
  k_fold<<<1024, 256, 0, stream>>>(Cp, B1);                       // G^16
  k_mmsplit<0><<<dim3(16, 16, 2), 256, 0, stream>>>(B1, disq, Cp);
  k_fold<<<1024, 256, 0, stream>>>(Cp, B3);                       // G^32

  // Stage C: 6 applies of G^32 (=192 powers), CholQR after each
  k_q0<<<192, 256, 0, stream>>>(Qa);
  for (int it = 0; it < 6; ++it) {
    float* src = (it & 1) ? Qb : Qa;
    float* dst = (it & 1) ? Qa : Qb;
    k_spmm<<<dim3(64, 4), 256, 0, stream>>>(B3, src, Zp);
    k_gram<<<32, 256, 0, stream>>>(Zp, dst, Sp);
    k_qr<<<4, 256, 0, stream>>>(Sp, dst);
  }
  // final orthonormal basis in Qa

  // Rayleigh-Ritz with G (exact Jacobi, 3 sweeps — PINNED)
  k_spmm<<<dim3(64, 4), 256, 0, stream>>>(B2, Qa, Zp);
  k_tbuild<<<32, 256, 0, stream>>>(Qa, Zp, Tp);
  k_jacobi<<<1, 448, 0, stream>>>(Tp, Vsel, s10);
  k_u10<<<4, 256, 0, stream>>>(Qa, Vsel, U10);

  // Stage A: GRU (after spectral path; h no longer aliased)
  k_gru<<<1024, 256, 0, stream>>>(x, wih, whh, bih, bhh, h);

  // Stage D: conv layers (256-blk chunked projection, fold in update)
  for (int l = 0; l < 3; ++l) {
    k_p0<<<256, 320, 0, stream>>>(h, U10, Pp);
    if (l < 2)
      k_update<0><<<dim3(64, 16), 256, 0, stream>>>(h, U10, Pp, convw + l * 1024,
                                                    s10, lw, lb, out);
    else
      k_update<1><<<dim3(64, 16), 256, 0, stream>>>(h, U10, Pp, convw + l * 1024,
                                                    s10, lw, lb, out);
  }
}

// Round 13
// 1072.336 us; speedup vs baseline: 1.3604x; 1.0535x over previous
//
#include <hip/hip_runtime.h>
#include <math.h>

// SpectralGCN: normalized Laplacian (fused into first matmul) -> G powers to
// G^32 (split-K full-grid matmuls + fold) -> 6x subspace applies with CholQR
// -> Rayleigh-Ritz Jacobi (3 sweeps PINNED [2 sweeps failed r10]; 1-barrier
// lookahead + pair-ownership update) -> GRU (packed-f32 math) -> 3 conv
// layers -> fused linear out. Cp aliases h: GRU runs after spectral path.
// Sizes: B=64, N=1024, F=8, T=12, H=32, K=10, OUT=12.

#define NN 1024
#define PP 48
#define JSWEEPS 3
#define NROUNDS (JSWEEPS * (PP - 1))

typedef float v2f __attribute__((ext_vector_type(2)));

// ---------------- GRU ----------------
// 4 waves/block, 64 rows/block; wave w computes channels [8w, 8w+8).
// Dot products as float2 packed math (v_pk_fma_f32): x-gates over f-pairs,
// h-gates over k-pairs (contiguous weights -> s_load_dwordx2/x8 pairs).
__global__ __launch_bounds__(256) void k_gru(
    const float* __restrict__ x, const float* __restrict__ wih,
    const float* __restrict__ whh, const float* __restrict__ bih,
    const float* __restrict__ bhh, float* __restrict__ hout) {
  __shared__ float s_x[64][97];
  __shared__ float s_h[64][33];
  int tid = threadIdx.x;
  int row = tid & 63;
  int i_base = __builtin_amdgcn_readfirstlane((tid >> 6) * 8);
  long row0 = (long)blockIdx.x * 64;

  for (int i = tid; i < 64 * 24; i += 256) {
    int r = i / 24, c = i % 24;
    float4 v = *(const float4*)&x[(row0 + r) * 96 + c * 4];
    s_x[r][c * 4 + 0] = v.x; s_x[r][c * 4 + 1] = v.y;
    s_x[r][c * 4 + 2] = v.z; s_x[r][c * 4 + 3] = v.w;
  }
  for (int i = tid; i < 64 * 32; i += 256) s_h[i / 32][i % 32] = 0.f;
  __syncthreads();

  v2f h2[16];
#pragma unroll
  for (int k2 = 0; k2 < 16; ++k2) h2[k2] = (v2f){0.f, 0.f};

  for (int t = 0; t < 12; ++t) {
    v2f x2[4];
#pragma unroll
    for (int f2 = 0; f2 < 4; ++f2)
      x2[f2] = (v2f){s_x[row][(2 * f2) * 12 + t], s_x[row][(2 * f2 + 1) * 12 + t]};
    for (int ii = 0; ii < 8; ++ii) {
      int i = i_base + ii;                  // wave-uniform
      const v2f* wr = (const v2f*)(wih + i * 8);
      const v2f* wz = (const v2f*)(wih + (32 + i) * 8);
      const v2f* wn = (const v2f*)(wih + (64 + i) * 8);
      const v2f* hr = (const v2f*)(whh + i * 32);
      const v2f* hz = (const v2f*)(whh + (32 + i) * 32);
      const v2f* hn = (const v2f*)(whh + (64 + i) * 32);
      v2f ar2 = (v2f){0.f, 0.f}, az2 = (v2f){0.f, 0.f};
      v2f gx2 = (v2f){0.f, 0.f}, gh2 = (v2f){0.f, 0.f};
#pragma unroll
      for (int f2 = 0; f2 < 4; ++f2) {
        ar2 += x2[f2] * wr[f2];
        az2 += x2[f2] * wz[f2];
        gx2 += x2[f2] * wn[f2];
      }
#pragma unroll
      for (int k2 = 0; k2 < 16; ++k2) {
        ar2 += h2[k2] * hr[k2];
        az2 += h2[k2] * hz[k2];
        gh2 += h2[k2] * hn[k2];
      }
      float ar = ar2.x + ar2.y + bih[i] + bhh[i];
      float az = az2.x + az2.y + bih[32 + i] + bhh[32 + i];
      float gx = gx2.x + gx2.y + bih[64 + i];
      float gh = gh2.x + gh2.y + bhh[64 + i];
      ar = fminf(fmaxf(ar, -30.f), 30.f);
      az = fminf(fmaxf(az, -30.f), 30.f);
      float r = __frcp_rn(1.f + __expf(-ar));
      float z = __frcp_rn(1.f + __expf(-az));
      float a = gx + r * gh;
      a = fminf(fmaxf(a, -15.f), 15.f);
      float e2 = __expf(2.f * a);
      float n = (e2 - 1.f) * __frcp_rn(e2 + 1.f);
      float hold = s_h[row][i];
      s_h[row][i] = (1.f - z) * n + z * hold;
    }
    __syncthreads();
#pragma unroll
    for (int k2 = 0; k2 < 16; ++k2)
      h2[k2] = (v2f){s_h[row][2 * k2], s_h[row][2 * k2 + 1]};
    __syncthreads();
  }
  for (int idx = tid; idx < 64 * 8; idx += 256) {
    int r = idx >> 3, c4 = idx & 7;
    float4 v = make_float4(s_h[r][c4 * 4], s_h[r][c4 * 4 + 1],
                           s_h[r][c4 * 4 + 2], s_h[r][c4 * 4 + 3]);
    *(float4*)&hout[(row0 + r) * 32 + c4 * 4] = v;
  }
}

// ---------------- graph build ----------------
__global__ void k_scatter(const int* __restrict__ ei, const float* __restrict__ ew,
                          float* __restrict__ A, int E) {
  int e = blockIdx.x * 256 + threadIdx.x;
  if (e < E) atomicAdd(&A[ei[e] * NN + ei[E + e]], ew[e]);
}

__global__ __launch_bounds__(256) void k_degree(const float* __restrict__ A,
                                                float* __restrict__ disq) {
  __shared__ float red[256];
  int row = blockIdx.x, tid = threadIdx.x;
  float s = 0.f;
  for (int j = tid; j < NN; j += 256) s += A[row * NN + j];
  red[tid] = s;
  __syncthreads();
  for (int off = 128; off > 0; off >>= 1) {
    if (tid < off) red[tid] += red[tid + off];
    __syncthreads();
  }
  if (tid == 0) disq[row] = 1.f / sqrtf(red[0]);
}

// ---- split-K symmetric matmul: Cp[z] = (rows x Khalf_z) partial of M*M^T --
// LAP=1: M = Lap on the fly from A,disq; LAP=0: M = A. grid (16,16,2).
template <int LAP>
__global__ __launch_bounds__(256) void k_mmsplit(const float* __restrict__ A,
                                                 const float* __restrict__ disq,
                                                 float* __restrict__ Cp) {
  __shared__ float As[32][68];
  __shared__ float Bs[32][68];
  int tid = threadIdx.x;
  int tx = tid & 15, ty = tid >> 4;
  int i0 = blockIdx.y * 64, j0 = blockIdx.x * 64;
  int kbase = blockIdx.z * 512;
  float acc[4][4];
#pragma unroll
  for (int a = 0; a < 4; ++a)
#pragma unroll
    for (int b = 0; b < 4; ++b) acc[a][b] = 0.f;
  int lrow = tid >> 3;
  int kk0 = (tid & 7) * 4;
  float drA0 = 0.f, drA1 = 0.f, drB0 = 0.f, drB1 = 0.f;
  if (LAP) {
    drA0 = disq[i0 + lrow]; drA1 = disq[i0 + lrow + 32];
    drB0 = disq[j0 + lrow]; drB1 = disq[j0 + lrow + 32];
  }
  float4 pa0 = *(const float4*)&A[(long)(i0 + lrow) * NN + kbase + kk0];
  float4 pa1 = *(const float4*)&A[(long)(i0 + lrow + 32) * NN + kbase + kk0];
  float4 pb0 = *(const float4*)&A[(long)(j0 + lrow) * NN + kbase + kk0];
  float4 pb1 = *(const float4*)&A[(long)(j0 + lrow + 32) * NN + kbase + kk0];
  for (int k0 = kbase; k0 < kbase + 512; k0 += 32) {
    if (LAP) {
      float4 dq = *(const float4*)&disq[k0 + kk0];
      int kg = k0 + kk0;
#pragma unroll
      for (int e = 0; e < 4; ++e) {
        float dqe = (e == 0) ? dq.x : (e == 1) ? dq.y : (e == 2) ? dq.z : dq.w;
        float a0e = (e == 0) ? pa0.x : (e == 1) ? pa0.y : (e == 2) ? pa0.z : pa0.w;
        float a1e = (e == 0) ? pa1.x : (e == 1) ? pa1.y : (e == 2) ? pa1.z : pa1.w;
        float b0e = (e == 0) ? pb0.x : (e == 1) ? pb0.y : (e == 2) ? pb0.z : pb0.w;
        float b1e = (e == 0) ? pb1.x : (e == 1) ? pb1.y : (e == 2) ? pb1.z : pb1.w;
        As[kk0 + e][lrow]      = -drA0 * a0e * dqe + ((i0 + lrow == kg + e) ? 1.f : 0.f);
        As[kk0 + e][lrow + 32] = -drA1 * a1e * dqe + ((i0 + lrow + 32 == kg + e) ? 1.f : 0.f);
        Bs[kk0 + e][lrow]      = -drB0 * b0e * dqe + ((j0 + lrow == kg + e) ? 1.f : 0.f);
        Bs[kk0 + e][lrow + 32] = -drB1 * b1e * dqe + ((j0 + lrow + 32 == kg + e) ? 1.f : 0.f);
      }
    } else {
      As[kk0 + 0][lrow] = pa0.x; As[kk0 + 1][lrow] = pa0.y;
      As[kk0 + 2][lrow] = pa0.z; As[kk0 + 3][lrow] = pa0.w;
      As[kk0 + 0][lrow + 32] = pa1.x; As[kk0 + 1][lrow + 32] = pa1.y;
      As[kk0 + 2][lrow + 32] = pa1.z; As[kk0 + 3][lrow + 32] = pa1.w;
      Bs[kk0 + 0][lrow] = pb0.x; Bs[kk0 + 1][lrow] = pb0.y;
      Bs[kk0 + 2][lrow] = pb0.z; Bs[kk0 + 3][lrow] = pb0.w;
      Bs[kk0 + 0][lrow + 32] = pb1.x; Bs[kk0 + 1][lrow + 32] = pb1.y;
      Bs[kk0 + 2][lrow + 32] = pb1.z; Bs[kk0 + 3][lrow + 32] = pb1.w;
    }
    __syncthreads();
    if (k0 + 32 < kbase + 512) {
      pa0 = *(const float4*)&A[(long)(i0 + lrow) * NN + k0 + 32 + kk0];
      pa1 = *(const float4*)&A[(long)(i0 + lrow + 32) * NN + k0 + 32 + kk0];
      pb0 = *(const float4*)&A[(long)(j0 + lrow) * NN + k0 + 32 + kk0];
      pb1 = *(const float4*)&A[(long)(j0 + lrow + 32) * NN + k0 + 32 + kk0];
    }
#pragma unroll
    for (int kk = 0; kk < 32; ++kk) {
      float4 av = *(const float4*)&As[kk][ty * 4];
      float4 bv = *(const float4*)&Bs[kk][tx * 4];
      float aa[4] = {av.x, av.y, av.z, av.w};
      float bb[4] = {bv.x, bv.y, bv.z, bv.w};
#pragma unroll
      for (int a = 0; a < 4; ++a)
#pragma unroll
        for (int b = 0; b < 4; ++b) acc[a][b] += aa[a] * bb[b];
    }
    __syncthreads();
  }
  float* cp = Cp + (long)blockIdx.z * (NN * NN);
#pragma unroll
  for (int a = 0; a < 4; ++a) {
    float4 v = make_float4(acc[a][0], acc[a][1], acc[a][2], acc[a][3]);
    *(float4*)&cp[(long)(i0 + ty * 4 + a) * NN + j0 + tx * 4] = v;
  }
}

// C = Cp[0] + Cp[1] (deterministic fold). grid 1024 x 256, float4/thread.
__global__ __launch_bounds__(256) void k_fold(const float* __restrict__ Cp,
                                              float* __restrict__ C) {
  int i = (blockIdx.x * 256 + threadIdx.x) * 4;
  float4 a = *(const float4*)&Cp[i];
  float4 b = *(const float4*)&Cp[i + NN * NN];
  float4 v = make_float4(a.x + b.x, a.y + b.y, a.z + b.z, a.w + b.w);
  *(float4*)&C[i] = v;
}

// ---------------- subspace iteration ----------------
__global__ void k_q0(float* __restrict__ Q) {
  int i = blockIdx.x * 256 + threadIdx.x;
  if (i < NN * PP) {
    unsigned u = (unsigned)i * 2654435761u;
    u ^= u >> 16; u *= 2246822519u; u ^= u >> 13; u *= 3266489917u; u ^= u >> 16;
    Q[i] = (float)(u & 0xFFFFFF) * (1.f / 16777216.f) - 0.5f;
  }
}

__global__ __launch_bounds__(256) void k_spmm(const float* __restrict__ Gp,
                                              const float* __restrict__ Q,
                                              float* __restrict__ Zp) {
  __shared__ float Qs[64][49];
  __shared__ float Gs[16][65];
  int tid = threadIdx.x;
  int r = tid >> 4;
  int c0 = (tid & 15) * 3;
  int row0 = blockIdx.x * 16;
  int k0 = blockIdx.y * 256;
  float a0 = 0.f, a1 = 0.f, a2 = 0.f;
  for (int kt = 0; kt < 4; ++kt) {
    int kb = k0 + kt * 64;
    for (int idx = tid; idx < 64 * PP; idx += 256) {
      int qr = idx / PP, qc = idx % PP;
      Qs[qr][qc] = Q[(kb + qr) * PP + qc];
    }
    for (int idx = tid; idx < 16 * 64; idx += 256) {
      int gr = idx >> 6, gk = idx & 63;
      Gs[gr][gk] = Gp[(long)(row0 + gr) * NN + kb + gk];
    }
    __syncthreads();
#pragma unroll 4
    for (int kk = 0; kk < 64; ++kk) {
      float g = Gs[r][kk];
      a0 += g * Qs[kk][c0];
      a1 += g * Qs[kk][c0 + 1];
      a2 += g * Qs[kk][c0 + 2];
    }
    __syncthreads();
  }
  float* zp = Zp + (long)blockIdx.y * (NN * PP);
  zp[(row0 + r) * PP + c0] = a0;
  zp[(row0 + r) * PP + c0 + 1] = a1;
  zp[(row0 + r) * PP + c0 + 2] = a2;
}

// Sum 4 partials -> Z, per-block Gram partial Sp[blk].
__global__ __launch_bounds__(256) void k_gram(const float* __restrict__ Zp,
                                              float* __restrict__ Z,
                                              float* __restrict__ Sp) {
  __shared__ float Zs[32][49];
  int tid = threadIdx.x;
  int r0 = blockIdx.x * 32;
  for (int idx = tid; idx < 32 * PP; idx += 256) {
    int r = idx / PP, c = idx % PP;
    long g = (long)(r0 + r) * PP + c;
    float s = Zp[g] + Zp[g + NN * PP] + Zp[g + 2 * NN * PP] + Zp[g + 3 * NN * PP];
    Zs[r][c] = s;
    Z[g] = s;
  }
  __syncthreads();
  float* sp = Sp + blockIdx.x * (PP * PP);
  for (int cell = tid; cell < PP * PP; cell += 256) {
    int i = cell / PP, j = cell % PP;
    float a = 0.f;
#pragma unroll 8
    for (int r = 0; r < 32; ++r) a += Zs[r][i] * Zs[r][j];
    sp[cell] = a;
  }
}

__global__ __launch_bounds__(256) void k_tbuild(const float* __restrict__ Qa,
                                                const float* __restrict__ Zp,
                                                float* __restrict__ Tp) {
  __shared__ float Qs[32][49];
  __shared__ float Ys[32][49];
  int tid = threadIdx.x;
  int r0 = blockIdx.x * 32;
  for (int idx = tid; idx < 32 * PP; idx += 256) {
    int r = idx / PP, c = idx % PP;
    long g = (long)(r0 + r) * PP + c;
    Qs[r][c] = Qa[g];
    Ys[r][c] = Zp[g] + Zp[g + NN * PP] + Zp[g + 2 * NN * PP] + Zp[g + 3 * NN * PP];
  }
  __syncthreads();
  float* tp = Tp + blockIdx.x * (PP * PP);
  for (int cell = tid; cell < PP * PP; cell += 256) {
    int i = cell / PP, j = cell % PP;
    float a = 0.f;
#pragma unroll 8
    for (int r = 0; r < 32; ++r) a += Qs[r][i] * Ys[r][j];
    tp[cell] = a;
  }
}

// Fused CholQR apply: factorize summed Gram, rows solve y R = q in registers.
__global__ __launch_bounds__(256) void k_qr(const float* __restrict__ Sp,
                                            float* __restrict__ Q) {
  __shared__ float R[PP][PP + 1];
  __shared__ float rs[PP];
  __shared__ float idiag[PP];
  int tid = threadIdx.x;
  for (int idx = tid; idx < PP * PP; idx += 256) {
    float s = 0.f;
    for (int b = 0; b < 32; ++b) s += Sp[b * (PP * PP) + idx];
    R[idx / PP][idx % PP] = s;
  }
  __syncthreads();
  for (int j = 0; j < PP; ++j) {
    float d = R[j][j];
    float sq = sqrtf(d > 1e-30f ? d : 1e-30f);
    float invd = 1.f / sq;
    for (int c = j + tid; c < PP; c += 256)
      rs[c] = (c == j) ? sq : R[j][c] * invd;
    __syncthreads();
    int m = PP - 1 - j;
    for (int idx = tid; idx < m * m; idx += 256) {
      int i = j + 1 + idx / m, c = j + 1 + idx % m;
      R[i][c] -= rs[i] * rs[c];
    }
    for (int c = j + tid; c < PP; c += 256) R[j][c] = rs[c];
    __syncthreads();
  }
  if (tid < PP) idiag[tid] = 1.f / R[tid][tid];
  __syncthreads();
  int row = blockIdx.x * 256 + tid;
  float q[PP];
#pragma unroll
  for (int k = 0; k < PP; ++k) q[k] = Q[row * PP + k];
#pragma unroll
  for (int c = 0; c < PP; ++c) {
    float s = q[c];
#pragma unroll
    for (int k = 0; k < c; ++k) s -= q[k] * R[k][c];
    q[c] = s * idiag[c];
  }
#pragma unroll
  for (int k = 0; k < PP; ++k) Q[row * PP + k] = q[k];
}

// Pipelined-lookahead cyclic Jacobi, 1 barrier/round, PAIR-ownership update:
// thread (i_row, pair k) reads the 4 T cells once and writes BOTH output
// columns (same math as column form, half the LDS reads). Wave 6 lanes 0-23
// compute round R+1 coefficients from pre-round state. 3 sweeps PINNED.
__global__ __launch_bounds__(448) void k_jacobi(const float* __restrict__ Tp,
                                                float* __restrict__ Vsel,
                                                float* __restrict__ s10) {
  __shared__ float Ta[PP][PP + 1], Tb[PP][PP + 1];
  __shared__ float Va[PP][PP + 1], Vb[PP][PP + 1];
  __shared__ float cw0[2][PP], cw1[2][PP];   // row-indexed weights
  __shared__ int ci0[2][PP], ci1[2][PP];     // row-indexed pair cols
  __shared__ int ppair[2][24], qpair[2][24]; // pair-indexed
  __shared__ float cpair[2][24], spair[2][24];
  __shared__ int selidx[10];
  int tid = threadIdx.x;
  for (int idx = tid; idx < PP * PP; idx += 448) {
    float s = 0.f;
    for (int b = 0; b < 32; ++b) s += Tp[b * (PP * PP) + idx];
    Tb[idx / PP][idx % PP] = s;
  }
  __syncthreads();
  for (int idx = tid; idx < PP * PP; idx += 448) {
    int i = idx / PP, j = idx % PP;
    Ta[i][j] = 0.5f * (Tb[i][j] + Tb[j][i]);
    Va[i][j] = (i == j) ? 1.f : 0.f;
  }
  if (tid < PP) {  // identity mapping in buffer 0
    ci0[0][tid] = tid; ci1[0][tid] = tid;
    cw0[0][tid] = 1.f; cw1[0][tid] = 0.f;
  }
  __syncthreads();
  float (*Tc)[PP + 1] = Ta, (*Tn)[PP + 1] = Tb;
  float (*Vc)[PP + 1] = Va, (*Vn)[PP + 1] = Vb;

  // coefficients for round rr into buffer nxt, viewing Tcur through the
  // rotations in buffer cur (identity => direct reads).
  auto coeff_phase = [&](int rr, int cur, int nxt, float (*Tcur)[PP + 1]) {
    int k = tid - 384;
    int P = (k == 0) ? 0 : ((rr + k - 1) % 47) + 1;
    int Q = ((rr + 46 - k) % 47) + 1;
    int P0 = ci0[cur][P], P1 = ci1[cur][P];
    float Pw0 = cw0[cur][P], Pw1 = cw1[cur][P];
    int Q0 = ci0[cur][Q], Q1 = ci1[cur][Q];
    float Qw0 = cw0[cur][Q], Qw1 = cw1[cur][Q];
    float app = Pw0 * (Pw0 * Tcur[P0][P0] + Pw1 * Tcur[P0][P1]) +
                Pw1 * (Pw0 * Tcur[P1][P0] + Pw1 * Tcur[P1][P1]);
    float apq = Pw0 * (Qw0 * Tcur[P0][Q0] + Qw1 * Tcur[P0][Q1]) +
                Pw1 * (Qw0 * Tcur[P1][Q0] + Qw1 * Tcur[P1][Q1]);
    float aqq = Qw0 * (Qw0 * Tcur[Q0][Q0] + Qw1 * Tcur[Q0][Q1]) +
                Qw1 * (Qw0 * Tcur[Q1][Q0] + Qw1 * Tcur[Q1][Q1]);
    float c = 1.f, s = 0.f;
    if (fabsf(apq) > 1e-30f) {
      float tau = (aqq - app) / (2.f * apq);
      float den = fabsf(tau) + sqrtf(1.f + tau * tau);
      float tt = copysignf(1.f / den, tau);
      c = 1.f / sqrtf(1.f + tt * tt);
      s = tt * c;
    }
    ci0[nxt][P] = P; ci1[nxt][P] = Q; cw0[nxt][P] = c;  cw1[nxt][P] = -s;
    ci0[nxt][Q] = P; ci1[nxt][Q] = Q; cw0[nxt][Q] = s;  cw1[nxt][Q] = c;
    ppair[nxt][k] = P; qpair[nxt][k] = Q;
    cpair[nxt][k] = c; spair[nxt][k] = s;
  };

  if (tid >= 384 && tid < 408) coeff_phase(0, 0, 1, Tc);
  __syncthreads();

  int cur = 1;
  int i_row = tid >> 3;          // valid for tid<384
  int kb = (tid & 7) * 3;        // 3 pairs per thread
  for (int R = 0; R < NROUNDS; ++R) {
    if (tid < 384) {
      float wi0 = cw0[cur][i_row], wi1 = cw1[cur][i_row];
      int i0 = ci0[cur][i_row], i1 = ci1[cur][i_row];
#pragma unroll
      for (int m = 0; m < 3; ++m) {
        int k = kb + m;
        int p = ppair[cur][k], q = qpair[cur][k];
        float c = cpair[cur][k], s = spair[cur][k];
        float t00 = Tc[i0][p], t01 = Tc[i0][q];
        float t10 = Tc[i1][p], t11 = Tc[i1][q];
        float rp = wi0 * t00 + wi1 * t10;
        float rq = wi0 * t01 + wi1 * t11;
        Tn[i_row][p] = c * rp - s * rq;
        Tn[i_row][q] = s * rp + c * rq;
        float v0 = Vc[i_row][p], v1 = Vc[i_row][q];
        Vn[i_row][p] = c * v0 - s * v1;
        Vn[i_row][q] = s * v0 + c * v1;
      }
    } else if (tid < 408 && R + 1 < NROUNDS) {
      coeff_phase((R + 1) % 47, cur, cur ^ 1, Tc);
    }
    __syncthreads();
    float (*tt_)[PP + 1] = Tc; Tc = Tn; Tn = tt_;
    float (*vt_)[PP + 1] = Vc; Vc = Vn; Vn = vt_;
    cur ^= 1;
  }

  if (tid < 64) {
    float v = (tid < PP) ? Tc[tid][tid] : -1e30f;
    for (int sel = 0; sel < 10; ++sel) {
      float bv = v; int bi = tid;
      for (int off = 32; off > 0; off >>= 1) {
        float ov = __shfl_xor(bv, off);
        int oi = __shfl_xor(bi, off);
        if (ov > bv || (ov == bv && oi < bi)) { bv = ov; bi = oi; }
      }
      if (tid == 0) { selidx[sel] = bi; s10[sel] = sqrtf(fmaxf(bv, 0.f)); }
      if (tid == bi) v = -1e30f;
    }
  }
  __syncthreads();
  for (int idx = tid; idx < PP * 10; idx += 448) {
    int j = idx / 10, i = idx % 10;
    Vsel[idx] = Vc[j][selidx[i]];
  }
}

// U10 = Qa * Vsel. grid 4 x 256.
__global__ __launch_bounds__(256) void k_u10(const float* __restrict__ Q,
                                             const float* __restrict__ Vsel,
                                             float* __restrict__ U10) {
  __shared__ float Vs[PP * 10];
  int tid = threadIdx.x;
  for (int idx = tid; idx < PP * 10; idx += 256) Vs[idx] = Vsel[idx];
  __syncthreads();
  int row = blockIdx.x * 256 + tid;
  float q[PP];
#pragma unroll
  for (int k = 0; k < PP; ++k) q[k] = Q[row * PP + k];
#pragma unroll
  for (int i = 0; i < 10; ++i) {
    float s = 0.f;
#pragma unroll
    for (int k = 0; k < PP; ++k) s += q[k] * Vs[k * 10 + i];
    U10[row * 10 + i] = s;
  }
}

// ---------------- conv layers ----------------
// P0 partials over 4 N-chunks: grid 256 (= 64 batches x 4 chunks).
__global__ __launch_bounds__(320) void k_p0(const float* __restrict__ h,
                                            const float* __restrict__ U10,
                                            float* __restrict__ Pp) {
  __shared__ float Hs[128][33];
  __shared__ float Us[128][10];
  int tid = threadIdx.x;
  int b = blockIdx.x >> 2, ch = blockIdx.x & 3;
  int i = tid / 32, kk = tid % 32;
  int base = ch * 256;
  float acc = 0.f;
  for (int t0 = 0; t0 < 256; t0 += 128) {
    for (int idx = tid; idx < 128 * 32; idx += 320) {
      int r = idx / 32, c = idx % 32;
      Hs[r][c] = h[(long)(b * NN + base + t0 + r) * 32 + c];
    }
    for (int idx = tid; idx < 1280; idx += 320)
      Us[idx / 10][idx % 10] = U10[(base + t0 + idx / 10) * 10 + idx % 10];
    __syncthreads();
#pragma unroll 8
    for (int r = 0; r < 128; ++r) acc += Us[r][i] * Hs[r][kk];
    __syncthreads();
  }
  Pp[(long)blockIdx.x * 320 + tid] = acc;
}

// Fold 4 P0 partials + P1 = s.*(P0 W), then h += relu(U10 * P1);
// LAST also emits out = h_new @ lw + lb.
template <int LAST>
__global__ __launch_bounds__(256) void k_update(float* __restrict__ h,
                                                const float* __restrict__ U10,
                                                const float* __restrict__ Pp,
                                                const float* __restrict__ W,
                                                const float* __restrict__ s10,
                                                const float* __restrict__ lw,
                                                const float* __restrict__ lb,
                                                float* __restrict__ out) {
  __shared__ float P0s[10][32];
  __shared__ float P1s[10][32];
  __shared__ float Ws[32][32];
  __shared__ float Us[64][10];
  __shared__ float hl[64][33];
  int tid = threadIdx.x;
  int b = blockIdx.x, n0 = blockIdx.y * 64;
  for (int idx = tid; idx < 320; idx += 256) {
    long g = (long)b * 4 * 320 + idx;
    P0s[idx / 32][idx % 32] = Pp[g] + Pp[g + 320] + Pp[g + 640] + Pp[g + 960];
  }
  for (int idx = tid; idx < 1024; idx += 256) Ws[idx / 32][idx % 32] = W[idx];
  for (int idx = tid; idx < 640; idx += 256)
    Us[idx / 10][idx % 10] = U10[(n0 + idx / 10) * 10 + idx % 10];
  __syncthreads();
  for (int idx = tid; idx < 320; idx += 256) {
    int i = idx / 32, kk = idx % 32;
    float a = 0.f;
#pragma unroll
    for (int j = 0; j < 32; ++j) a += P0s[i][j] * Ws[j][kk];
    P1s[i][kk] = s10[i] * a;
  }
  __syncthreads();
  for (int idx = tid; idx < 2048; idx += 256) {
    int nl = idx / 32, k = idx % 32;
    float z = 0.f;
#pragma unroll
    for (int i = 0; i < 10; ++i) z += Us[nl][i] * P1s[i][k];
    long g = (long)(b * NN + n0 + nl) * 32 + k;
    float hn = h[g] + fmaxf(z, 0.f);
    if (LAST) hl[nl][k] = hn;
    else h[g] = hn;
  }
  if (LAST) {
    __syncthreads();
    for (int idx = tid; idx < 64 * 12; idx += 256) {
      int row = idx / 12, o = idx % 12;
      float s = lb[o];
#pragma unroll
      for (int j = 0; j < 32; ++j) s += hl[row][j] * lw[j * 12 + o];
      out[(long)(b * NN + n0 + row) * 12 + o] = s;
    }
  }
}

extern "C" void kernel_launch(void* const* d_in, const int* in_sizes, int n_in,
                              void* d_out, int out_size, void* d_ws, size_t ws_size,
                              hipStream_t stream) {
  const float* x    = (const float*)d_in[0];
  const int*   ei   = (const int*)d_in[1];
  const float* ew   = (const float*)d_in[2];
  const float* wih  = (const float*)d_in[3];
  const float* whh  = (const float*)d_in[4];
  const float* bih  = (const float*)d_in[5];
  const float* bhh  = (const float*)d_in[6];
  const float* convw = (const float*)d_in[7];
  const float* lw   = (const float*)d_in[8];
  const float* lb   = (const float*)d_in[9];
  float* out = (float*)d_out;
  float* ws  = (float*)d_ws;
  int E = in_sizes[1] / 2;

  float* h    = ws;                 // 2097152 (aliased as Cp during stage B)
  float* B1   = h + 2097152;        // 1048576
  float* B2   = B1 + 1048576;       // 1048576
  float* B3   = B2 + 1048576;       // 1048576
  float* Qa   = B3 + 1048576;       // 49152
  float* Qb   = Qa + 49152;         // 49152
  float* Zp   = Qb + 49152;         // 196608 (aliased as Pp in stage D)
  float* Sp   = Zp + 196608;        // 73728
  float* Tp   = Sp + 73728;         // 73728
  float* Vsel = Tp + 73728;         // 480
  float* s10  = Vsel + 480;         // 16
  float* U10  = s10 + 16;           // 10240
  float* disq = U10 + 10240;        // 1024
  float* Pp   = Zp;                 // alias
  float* Cp   = h;                  // 2x 1048576 split-K partials (alias)

  // Stage B first (Cp aliases h; GRU comes after the spectral path)
  hipMemsetAsync(B1, 0, (size_t)1048576 * 4, stream);
  k_scatter<<<(E + 255) / 256, 256, 0, stream>>>(ei, ew, B1, E);
  k_degree<<<NN, 256, 0, stream>>>(B1, disq);
  k_mmsplit<1><<<dim3(16, 16, 2), 256, 0, stream>>>(B1, disq, Cp);
  k_fold<<<1024, 256, 0, stream>>>(Cp, B2);                       // G
  k_mmsplit<0><<<dim3(16, 16, 2), 256, 0, stream>>>(B2, disq, Cp);
  k_fold<<<1024, 256, 0, stream>>>(Cp, B3);                       // G^2
  k_mmsplit<0><<<dim3(16, 16, 2), 256, 0, stream>>>(B3, disq, Cp);
  k_fold<<<1024, 256, 0, stream>>>(Cp, B1);                       // G^4
  k_mmsplit<0><<<dim3(16, 16, 2), 256, 0, stream>>>(B1, disq, Cp);
  k_fold<<<1024, 256, 0, stream>>>(Cp, B3);                       // G^8
  k_mmsplit<0><<<dim3(16, 16, 2), 256, 0, stream>>>(B3, disq, Cp);
  k_fold<<<1024, 256, 0, stream>>>(Cp, B1);                       // G^16
  k_mmsplit<0><<<dim3(16, 16, 2), 256, 0, stream>>>(B1, disq, Cp);
  k_fold<<<1024, 256, 0, stream>>>(Cp, B3);                       // G^32

  // Stage C: 6 applies of G^32 (=192 powers), CholQR after each
  k_q0<<<192, 256, 0, stream>>>(Qa);
  for (int it = 0; it < 6; ++it) {
    float* src = (it & 1) ? Qb : Qa;
    float* dst = (it & 1) ? Qa : Qb;
    k_spmm<<<dim3(64, 4), 256, 0, stream>>>(B3, src, Zp);
    k_gram<<<32, 256, 0, stream>>>(Zp, dst, Sp);
    k_qr<<<4, 256, 0, stream>>>(Sp, dst);
  }
  // final orthonormal basis in Qa

  // Rayleigh-Ritz with G (exact Jacobi, 3 sweeps — PINNED)
  k_spmm<<<dim3(64, 4), 256, 0, stream>>>(B2, Qa, Zp);
  k_tbuild<<<32, 256, 0, stream>>>(Qa, Zp, Tp);
  k_jacobi<<<1, 448, 0, stream>>>(Tp, Vsel, s10);
  k_u10<<<4, 256, 0, stream>>>(Qa, Vsel, U10);

  // Stage A: GRU (after spectral path; h no longer aliased)
  k_gru<<<1024, 256, 0, stream>>>(x, wih, whh, bih, bhh, h);

  // Stage D: conv layers (256-blk chunked projection, fold in update)
  for (int l = 0; l < 3; ++l) {
    k_p0<<<256, 320, 0, stream>>>(h, U10, Pp);
    if (l < 2)
      k_update<0><<<dim3(64, 16), 256, 0, stream>>>(h, U10, Pp, convw + l * 1024,
                                                    s10, lw, lb, out);
    else
      k_update<1><<<dim3(64, 16), 256, 0, stream>>>(h, U10, Pp, convw + l * 1024,
                                                    s10, lw, lb, out);
  }
}